// Round 1
// baseline (6289.180 us; speedup 1.0000x reference)
//
#include <hip/hip_runtime.h>

// ---------------- elementwise kernels ----------------

__global__ void k_build_XsA(const float* __restrict__ adj,
                            const float* __restrict__ alpha,
                            float* __restrict__ Xs, int n, float scale)
{
    int j = blockIdx.x * 256 + threadIdx.x;
    int i = blockIdx.y;
    if (j >= n) return;
    float s = 1.f / (1.f + expf(-alpha[i]));
    float v = adj[(size_t)i * n + j] - (i == j ? 1.f : 0.f);
    Xs[(size_t)i * n + j] = scale * s * v;
}

__global__ void k_init_EP(const float* __restrict__ Xs,
                          float* __restrict__ E, float* __restrict__ P, int n)
{
    int j = blockIdx.x * 256 + threadIdx.x;
    int i = blockIdx.y;
    if (j >= n) return;
    size_t idx = (size_t)i * n + j;
    float v = Xs[idx];
    float id = (i == j) ? 1.f : 0.f;
    E[idx] = id + v;
    if (P) P[idx] = id + 0.5f * v;
}

__global__ void k_build_wd(const float* __restrict__ w,
                           const float* __restrict__ d,
                           float* __restrict__ wd, int h)
{
    int k = blockIdx.x * 256 + threadIdx.x;
    int i = blockIdx.y;
    if (k >= h) return;
    float dc = fminf(fmaxf(d[k], 0.f), 1.f);
    wd[(size_t)i * h + k] = w[(size_t)i * h + k] * dc;
}

__global__ void k_transpose(const float* __restrict__ in,
                            float* __restrict__ out, int n)
{
    __shared__ float tile[32][33];
    int bx = blockIdx.x * 32, by = blockIdx.y * 32;
    int tx = threadIdx.x, ty = threadIdx.y;
    #pragma unroll
    for (int r = 0; r < 32; r += 8)
        tile[ty + r][tx] = in[(size_t)(by + ty + r) * n + bx + tx];
    __syncthreads();
    #pragma unroll
    for (int r = 0; r < 32; r += 8)
        out[(size_t)(bx + ty + r) * n + by + tx] = tile[tx][ty + r];
}

// ---------------- tiled f32 GEMM ----------------
// C = alpha*(A@B) [+ beta*D] [+ diag on the diagonal]
// optionally E += C-value, P += pfac * C-value  (dual Taylor accumulation)
// Row-major. M % (16*TM) == 0, N % (16*TN) == 0, K % 16 == 0 required.

template<int TM, int TN>
__global__ __launch_bounds__(256)
void gemm_f32(const float* __restrict__ A, const float* __restrict__ B,
              float* __restrict__ C, const float* __restrict__ D,
              float* __restrict__ E, float* __restrict__ P,
              int M, int N, int K,
              float alpha, float beta, float pfac, float diag)
{
    constexpr int BM = 16 * TM, BN = 16 * TN, BK = 16;
    __shared__ float As[BK][BM];   // A tile, transposed: As[k][m]
    __shared__ float Bs[BK][BN];   // B tile: Bs[k][n]

    const int tid = threadIdx.x;
    const int tr = tid >> 4, tc = tid & 15;
    const int brow = blockIdx.y * BM, bcol = blockIdx.x * BN;

    float acc[TM][TN];
    #pragma unroll
    for (int i = 0; i < TM; ++i)
        #pragma unroll
        for (int j = 0; j < TN; ++j) acc[i][j] = 0.f;

    constexpr int ALOADS = (BM * BK) / (256 * 4);   // float4s per thread
    constexpr int BLOADS = (BN * BK) / (256 * 4);

    for (int k0 = 0; k0 < K; k0 += BK) {
        #pragma unroll
        for (int l = 0; l < ALOADS; ++l) {
            int fid = l * 256 + tid;
            int r = fid >> 2;          // BK/4 = 4 float4 per row
            int c4 = fid & 3;
            const float4 v = *reinterpret_cast<const float4*>(
                A + (size_t)(brow + r) * K + k0 + c4 * 4);
            As[c4 * 4 + 0][r] = v.x;
            As[c4 * 4 + 1][r] = v.y;
            As[c4 * 4 + 2][r] = v.z;
            As[c4 * 4 + 3][r] = v.w;
        }
        #pragma unroll
        for (int l = 0; l < BLOADS; ++l) {
            int fid = l * 256 + tid;
            int r = fid / (BN / 4);
            int c4 = fid % (BN / 4);
            *reinterpret_cast<float4*>(&Bs[r][c4 * 4]) =
                *reinterpret_cast<const float4*>(
                    B + (size_t)(k0 + r) * N + bcol + c4 * 4);
        }
        __syncthreads();
        #pragma unroll
        for (int kk = 0; kk < BK; ++kk) {
            float af[TM], bf[TN];
            #pragma unroll
            for (int i = 0; i < TM; i += 4)
                *reinterpret_cast<float4*>(&af[i]) =
                    *reinterpret_cast<const float4*>(&As[kk][tr * TM + i]);
            #pragma unroll
            for (int j = 0; j < TN; j += 4)
                *reinterpret_cast<float4*>(&bf[j]) =
                    *reinterpret_cast<const float4*>(&Bs[kk][tc * TN + j]);
            #pragma unroll
            for (int i = 0; i < TM; ++i)
                #pragma unroll
                for (int j = 0; j < TN; ++j)
                    acc[i][j] = fmaf(af[i], bf[j], acc[i][j]);
        }
        __syncthreads();
    }

    #pragma unroll
    for (int i = 0; i < TM; ++i) {
        const int r = brow + tr * TM + i;
        #pragma unroll
        for (int j = 0; j < TN; ++j) {
            const int c = bcol + tc * TN + j;
            const size_t idx = (size_t)r * N + c;
            float v = alpha * acc[i][j];
            if (D) v = fmaf(beta, D[idx], v);
            if (diag != 0.f && r == c) v += diag;
            C[idx] = v;
            if (E) E[idx] += v;
            if (P) P[idx] += pfac * v;
        }
    }
}

// ---------------- host orchestration ----------------

extern "C" void kernel_launch(void* const* d_in, const int* in_sizes, int n_in,
                              void* d_out, int out_size, void* d_ws, size_t ws_size,
                              hipStream_t stream)
{
    const float* x     = (const float*)d_in[0];   // [n, h]
    const float* x0    = (const float*)d_in[1];   // [n, h]
    const float* adj   = (const float*)d_in[2];   // [n, n]
    const float* alpha = (const float*)d_in[3];   // [n]
    const float* w     = (const float*)d_in[4];   // [h, h]
    const float* dvec  = (const float*)d_in[5];   // [h]

    const int n = in_sizes[3];      // 2048
    const int h = in_sizes[5];      // 1024
    const size_t nn = (size_t)n * n;
    const size_t nh = (size_t)n * h;
    const size_t hh = (size_t)h * h;

    float* ws  = (float*)d_ws;
    // A-phase buffers (5 x nn floats = 80 MiB at n=2048)
    float* XsA = ws;            // dt*A
    float* t0  = XsA + nn;
    float* t1  = t0 + nn;
    float* Ea  = t1 + nn;       // m1_L = e^{dt A}
    float* Pa  = Ea + nn;       // phi1(dt A)   (m2 = dt * Pa)
    // B-phase (reuses XsA/t0 regions; A-Taylor is done by then)
    float* wd  = XsA;           // hh
    float* wT  = wd + hh;       // hh
    float* XsB = wT + hh;       // hh  dt*B
    float* bt0 = XsB + hh;      // hh
    float* bt1 = t0;            // hh
    float* Eb  = bt1 + hh;      // hh  m1_R = e^{dt B}  (persists)
    // phase 3 (reuses t1 and XsA regions)
    float* forcing = t1;        // nh
    float* tb      = t1 + nh;   // nh
    float* za      = XsA;       // nh (wd/wT dead by now)

    const dim3 blk(256);
    const float dt = 0.1f;

    // 1) XsA = dt * A = 0.05 * sigmoid(alpha)_i * (adj - I)
    k_build_XsA<<<dim3(n / 256, n), blk, 0, stream>>>(adj, alpha, XsA, n, 0.5f * dt);

    // 2) Ea = I + X, Pa = I + X/2   (Taylor orders 0,1 of e^X and phi1(X))
    k_init_EP<<<dim3(n / 256, n), blk, 0, stream>>>(XsA, Ea, Pa, n);

    // 3) A-side Taylor k = 2..9: term <- term@X / k; Ea += term; Pa += term/(k+1)
    {
        const float* term = XsA;
        float* outb = t0;
        for (int k = 2; k <= 9; ++k) {
            gemm_f32<8, 8><<<dim3(n / 128, n / 128), blk, 0, stream>>>(
                term, XsA, outb, nullptr, Ea, Pa, n, n, n,
                1.f / (float)k, 0.f, 1.f / (float)(k + 1), 0.f);
            term = outb;
            outb = (outb == t0) ? t1 : t0;
        }
    }

    // 4) B side: XsB = dt*(w*diag(clip(d)) @ w^T - I); Eb = e^{XsB} (Taylor order 12)
    k_build_wd<<<dim3(h / 256, h), blk, 0, stream>>>(w, dvec, wd, h);
    k_transpose<<<dim3(h / 32, h / 32), dim3(32, 8), 0, stream>>>(w, wT, h);
    gemm_f32<4, 4><<<dim3(h / 64, h / 64), blk, 0, stream>>>(
        wd, wT, XsB, nullptr, nullptr, nullptr, h, h, h, dt, 0.f, 0.f, -dt);
    k_init_EP<<<dim3(h / 256, h), blk, 0, stream>>>(XsB, Eb, nullptr, h);
    {
        const float* term = XsB;
        float* outb = bt0;
        for (int k = 2; k <= 12; ++k) {
            gemm_f32<4, 4><<<dim3(h / 64, h / 64), blk, 0, stream>>>(
                term, XsB, outb, nullptr, Eb, nullptr, h, h, h,
                1.f / (float)k, 0.f, 0.f, 0.f);
            term = outb;
            outb = (outb == bt0) ? bt1 : bt0;
        }
    }

    // 5) forcing = m2 @ x0 = dt * (Pa @ x0)
    gemm_f32<4, 8><<<dim3(h / 128, n / 64), blk, 0, stream>>>(
        Pa, x0, forcing, nullptr, nullptr, nullptr, n, h, n, dt, 0.f, 0.f, 0.f);

    // 6) scan: z <- m1_L @ z @ m1_R + forcing, 9 steps (int(1.0//0.1) == 9)
    const float* zin = x;
    for (int s = 1; s <= 9; ++s) {
        gemm_f32<4, 8><<<dim3(h / 128, n / 64), blk, 0, stream>>>(
            Ea, zin, tb, nullptr, nullptr, nullptr, n, h, n, 1.f, 0.f, 0.f, 0.f);
        float* zout = (s & 1) ? (float*)d_out : za;
        gemm_f32<4, 8><<<dim3(h / 128, n / 64), blk, 0, stream>>>(
            tb, Eb, zout, forcing, nullptr, nullptr, n, h, h, 1.f, 1.f, 0.f, 0.f);
        zin = zout;
    }
}

// Round 2
// 2376.702 us; speedup vs baseline: 2.6462x; 2.6462x over previous
//
#include <hip/hip_runtime.h>

typedef __attribute__((ext_vector_type(8))) short short8v;
typedef __attribute__((ext_vector_type(4))) float f32x4;

typedef const __attribute__((address_space(1))) void gvoid_t;
typedef __attribute__((address_space(3))) void svoid_t;

__device__ __forceinline__ unsigned short f2b(float f) {
    unsigned u = __float_as_uint(f);
    unsigned r = (u + 0x7fffu + ((u >> 16) & 1u)) >> 16;
    return (unsigned short)r;
}
__device__ __forceinline__ float b2f(unsigned short h) {
    return __uint_as_float((unsigned)h << 16);
}

// ---------------- elementwise / setup kernels ----------------

__global__ void k_build_XsA(const float* __restrict__ adj,
                            const float* __restrict__ alpha,
                            float* __restrict__ Xs, int n, float scale)
{
    int j = blockIdx.x * 256 + threadIdx.x;
    int i = blockIdx.y;
    if (j >= n) return;
    float s = 1.f / (1.f + expf(-alpha[i]));
    float v = adj[(size_t)i * n + j] - (i == j ? 1.f : 0.f);
    Xs[(size_t)i * n + j] = scale * s * v;
}

__global__ void k_init_EP(const float* __restrict__ Xs,
                          float* __restrict__ E, float* __restrict__ P, int n)
{
    int j = blockIdx.x * 256 + threadIdx.x;
    int i = blockIdx.y;
    if (j >= n) return;
    size_t idx = (size_t)i * n + j;
    float v = Xs[idx];
    float id = (i == j) ? 1.f : 0.f;
    E[idx] = id + v;
    if (P) P[idx] = id + 0.5f * v;
}

__global__ void k_build_wd(const float* __restrict__ w,
                           const float* __restrict__ d,
                           float* __restrict__ wd, int h)
{
    int k = blockIdx.x * 256 + threadIdx.x;
    int i = blockIdx.y;
    if (k >= h) return;
    float dc = fminf(fmaxf(d[k], 0.f), 1.f);
    wd[(size_t)i * h + k] = w[(size_t)i * h + k] * dc;
}

// f32 -> bf16 hi (and optional lo residual), row-major, vectorized x4
__global__ void k_split(const float* __restrict__ in,
                        unsigned short* __restrict__ hi,
                        unsigned short* __restrict__ lo, int count4)
{
    int i = blockIdx.x * 256 + threadIdx.x;
    if (i >= count4) return;
    float4 v = ((const float4*)in)[i];
    ushort4 h;
    h.x = f2b(v.x); h.y = f2b(v.y); h.z = f2b(v.z); h.w = f2b(v.w);
    ((ushort4*)hi)[i] = h;
    if (lo) {
        ushort4 l;
        l.x = f2b(v.x - b2f(h.x));
        l.y = f2b(v.y - b2f(h.y));
        l.z = f2b(v.z - b2f(h.z));
        l.w = f2b(v.w - b2f(h.w));
        ((ushort4*)lo)[i] = l;
    }
}

// transpose + split: in[R][C] f32 -> hiT/loT[C][R] bf16
__global__ void k_tsplit(const float* __restrict__ in,
                         unsigned short* __restrict__ hiT,
                         unsigned short* __restrict__ loT, int R, int C)
{
    __shared__ float tile[32][33];
    int bx = blockIdx.x * 32, by = blockIdx.y * 32;
    int tx = threadIdx.x, ty = threadIdx.y;
    #pragma unroll
    for (int r = 0; r < 32; r += 8)
        tile[ty + r][tx] = in[(size_t)(by + ty + r) * C + bx + tx];
    __syncthreads();
    #pragma unroll
    for (int r = 0; r < 32; r += 8) {
        float v = tile[tx][ty + r];
        size_t o = (size_t)(bx + ty + r) * R + by + tx;
        unsigned short hh = f2b(v);
        hiT[o] = hh;
        if (loT) loT[o] = f2b(v - b2f(hh));
    }
}

// ---------------- bf16 MFMA GEMM ----------------
// C_f32 = alpha*(A@B) [+ C (accum)] [+ beta*D] [+ diag*I]; optional bf16
// hi/lo outputs Cb/Cb2; optional E += v, P += pfac*v.
// A: M x K bf16 row-major.  BT: N x K bf16 row-major (i.e. B transposed).
// Tile: BM = FM*32 rows, BN = FN*32 cols, BK=32. 4 waves in 2x2.
// Requires M%BM==0, N%BN==0, K%32==0.

template<int FM, int FN>
__global__ __launch_bounds__(256)
void gemm_bf16(const unsigned short* __restrict__ A,
               const unsigned short* __restrict__ BT,
               float* __restrict__ C,
               unsigned short* __restrict__ Cb,
               unsigned short* __restrict__ Cb2,
               const float* __restrict__ D,
               float* __restrict__ E, float* __restrict__ P,
               int M, int N, int K,
               float alpha, float beta, float pfac, float diag, int accum)
{
    constexpr int BM = FM * 32, BN = FN * 32, BK = 32;
    __shared__ unsigned short As[BM * BK];
    __shared__ unsigned short Bs[BN * BK];

    const int tid  = threadIdx.x;
    const int lane = tid & 63;
    const int wave = tid >> 6;
    const int wr = wave >> 1, wc = wave & 1;
    const int l16 = lane & 15, l4 = lane >> 4;
    const int brow = blockIdx.y * BM, bcol = blockIdx.x * BN;

    f32x4 acc[FM][FN];
    #pragma unroll
    for (int m = 0; m < FM; ++m)
        #pragma unroll
        for (int nn2 = 0; nn2 < FN; ++nn2)
            acc[m][nn2] = (f32x4){0.f, 0.f, 0.f, 0.f};

    constexpr int AIT = BM / 64;   // global_load_lds per thread for A tile
    constexpr int BIT = BN / 64;

    const unsigned short* Ab = A + (size_t)brow * K;
    const unsigned short* Bb = BT + (size_t)bcol * K;

    for (int k0 = 0; k0 < K; k0 += BK) {
        #pragma unroll
        for (int it = 0; it < AIT; ++it) {
            int cb = it * 256 + wave * 64;           // wave-uniform chunk base
            int chunk = cb + lane;
            int r = chunk >> 2, c8 = (chunk & 3) * 8;
            __builtin_amdgcn_global_load_lds(
                (gvoid_t*)(Ab + (size_t)r * K + k0 + c8),
                (svoid_t*)(As + cb * 8), 16, 0, 0);
        }
        #pragma unroll
        for (int it = 0; it < BIT; ++it) {
            int cb = it * 256 + wave * 64;
            int chunk = cb + lane;
            int r = chunk >> 2, c8 = (chunk & 3) * 8;
            __builtin_amdgcn_global_load_lds(
                (gvoid_t*)(Bb + (size_t)r * K + k0 + c8),
                (svoid_t*)(Bs + cb * 8), 16, 0, 0);
        }
        __syncthreads();

        short8v af[FM], bfr[FN];
        #pragma unroll
        for (int m = 0; m < FM; ++m)
            af[m] = *(const short8v*)&As[(wr * FM * 16 + m * 16 + l16) * BK + l4 * 8];
        #pragma unroll
        for (int nn2 = 0; nn2 < FN; ++nn2)
            bfr[nn2] = *(const short8v*)&Bs[(wc * FN * 16 + nn2 * 16 + l16) * BK + l4 * 8];
        #pragma unroll
        for (int m = 0; m < FM; ++m)
            #pragma unroll
            for (int nn2 = 0; nn2 < FN; ++nn2)
                acc[m][nn2] = __builtin_amdgcn_mfma_f32_16x16x32_bf16(
                    af[m], bfr[nn2], acc[m][nn2], 0, 0, 0);
        __syncthreads();
    }

    #pragma unroll
    for (int m = 0; m < FM; ++m) {
        #pragma unroll
        for (int nn2 = 0; nn2 < FN; ++nn2) {
            #pragma unroll
            for (int q = 0; q < 4; ++q) {
                int row = brow + wr * FM * 16 + m * 16 + l4 * 4 + q;
                int col = bcol + wc * FN * 16 + nn2 * 16 + l16;
                size_t idx = (size_t)row * N + col;
                float v = alpha * acc[m][nn2][q];
                if (accum) v += C[idx];
                if (D) v = fmaf(beta, D[idx], v);
                if (diag != 0.f && row == col) v += diag;
                if (C) C[idx] = v;
                if (Cb) {
                    unsigned short hb = f2b(v);
                    Cb[idx] = hb;
                    if (Cb2) Cb2[idx] = f2b(v - b2f(hb));
                }
                if (E) E[idx] += v;
                if (P) P[idx] += pfac * v;
            }
        }
    }
}

// ---------------- host orchestration ----------------

extern "C" void kernel_launch(void* const* d_in, const int* in_sizes, int n_in,
                              void* d_out, int out_size, void* d_ws, size_t ws_size,
                              hipStream_t stream)
{
    const float* x     = (const float*)d_in[0];   // [n, h]
    const float* x0    = (const float*)d_in[1];   // [n, h]
    const float* adj   = (const float*)d_in[2];   // [n, n]
    const float* alpha = (const float*)d_in[3];   // [n]
    const float* w     = (const float*)d_in[4];   // [h, h]
    const float* dvec  = (const float*)d_in[5];   // [h]

    const int n = in_sizes[3];      // 2048
    const int h = in_sizes[5];      // 1024
    const size_t MB = 1u << 20;
    char* ws = (char*)d_ws;

    const size_t nn = (size_t)n * n;
    const size_t nh = (size_t)n * h;
    const size_t hh = (size_t)h * h;

    // ---- workspace layout (byte offsets in MiB), phase-overlaid ----
    float*          XsA    = (float*)(ws + 0 * MB);    // 16 MB (phase A)
    unsigned short* termA  = (unsigned short*)(ws + 0 * MB);   // 8 MB
    unsigned short* termB  = (unsigned short*)(ws + 8 * MB);   // 8 MB
    unsigned short* Eah    = (unsigned short*)(ws + 0 * MB);   // 8 MB (phase C)
    unsigned short* Eal    = (unsigned short*)(ws + 8 * MB);   // 8 MB
    unsigned short* XsA_b  = (unsigned short*)(ws + 16 * MB);  // 8 MB
    unsigned short* zTh    = (unsigned short*)(ws + 16 * MB);  // 4 MB (phase C)
    unsigned short* zTl    = (unsigned short*)(ws + 20 * MB);  // 4 MB
    unsigned short* XsAT_b = (unsigned short*)(ws + 24 * MB);  // 8 MB
    float*          za     = (float*)(ws + 24 * MB);           // 8 MB (phase C)
    float*          Ea     = (float*)(ws + 32 * MB);   // 16 MB
    unsigned short* Pab    = (unsigned short*)(ws + 32 * MB);  // 8 MB (phase C)
    unsigned short* x0T    = (unsigned short*)(ws + 40 * MB);  // 4 MB (phase C)
    float*          Pa     = (float*)(ws + 48 * MB);   // 16 MB
    float*          tb     = (float*)(ws + 48 * MB);           // 8 MB (phase C)
    unsigned short* tbh    = (unsigned short*)(ws + 56 * MB);  // 4 MB
    unsigned short* tbl    = (unsigned short*)(ws + 60 * MB);  // 4 MB
    float*          wd     = (float*)(ws + 64 * MB);   // 4 MB (phase B)
    float*          XsB    = (float*)(ws + 64 * MB);   // 4 MB
    unsigned short* EbTh   = (unsigned short*)(ws + 64 * MB);  // 2 MB (late B)
    unsigned short* EbTl   = (unsigned short*)(ws + 66 * MB);  // 2 MB
    unsigned short* wdh    = (unsigned short*)(ws + 68 * MB);  // 2 MB
    unsigned short* wdl    = (unsigned short*)(ws + 70 * MB);  // 2 MB
    float*          Eb     = (float*)(ws + 68 * MB);           // 4 MB
    unsigned short* wh     = (unsigned short*)(ws + 72 * MB);  // 2 MB
    unsigned short* wl     = (unsigned short*)(ws + 74 * MB);  // 2 MB
    unsigned short* btA    = (unsigned short*)(ws + 72 * MB);  // 2 MB
    unsigned short* btB    = (unsigned short*)(ws + 74 * MB);  // 2 MB
    unsigned short* XsB_b  = (unsigned short*)(ws + 76 * MB);  // 2 MB
    unsigned short* XsBT_b = (unsigned short*)(ws + 78 * MB);  // 2 MB
    float*          forcing= (float*)(ws + 72 * MB);           // 8 MB (phase C)

    const dim3 blk(256);
    const float dt = 0.1f;

    // ============ Phase A: Ea = e^{dtA}, Pa = phi1(dtA) ============
    k_build_XsA<<<dim3(n / 256, n), blk, 0, stream>>>(adj, alpha, XsA, n, 0.5f * dt);
    k_split<<<dim3((int)(nn / 4 / 256)), blk, 0, stream>>>(XsA, XsA_b, nullptr, (int)(nn / 4));
    k_tsplit<<<dim3(n / 32, n / 32), dim3(32, 8), 0, stream>>>(XsA, XsAT_b, nullptr, n, n);
    k_init_EP<<<dim3(n / 256, n), blk, 0, stream>>>(XsA, Ea, Pa, n);

    {   // Taylor terms k=2..5 (||dtA|| ~ 0.075 -> trunc ~2e-10)
        const unsigned short* a = XsA_b;
        unsigned short* outs[4] = {termA, termB, termA, termB};
        for (int k = 2; k <= 5; ++k) {
            gemm_bf16<4, 4><<<dim3(n / 128, n / 128), blk, 0, stream>>>(
                a, XsAT_b, nullptr, outs[k - 2], nullptr, nullptr, Ea, Pa,
                n, n, n, 1.f / (float)k, 0.f, 1.f / (float)(k + 1), 0.f, 0);
            a = outs[k - 2];
        }
    }

    // ============ Phase B: Eb = e^{dtB} ============
    k_build_wd<<<dim3(h / 256, h), blk, 0, stream>>>(w, dvec, wd, h);
    k_split<<<dim3((int)(hh / 4 / 256)), blk, 0, stream>>>(wd, wdh, wdl, (int)(hh / 4));
    k_split<<<dim3((int)(hh / 4 / 256)), blk, 0, stream>>>(w, wh, wl, (int)(hh / 4));
    // XsB = dt*(wd @ w^T) - dt*I   (split product, 3 GEMMs; BT of w^T is w)
    gemm_bf16<2, 2><<<dim3(h / 64, h / 64), blk, 0, stream>>>(
        wdh, wh, XsB, nullptr, nullptr, nullptr, nullptr, nullptr,
        h, h, h, dt, 0.f, 0.f, -dt, 0);
    gemm_bf16<2, 2><<<dim3(h / 64, h / 64), blk, 0, stream>>>(
        wdh, wl, XsB, nullptr, nullptr, nullptr, nullptr, nullptr,
        h, h, h, dt, 0.f, 0.f, 0.f, 1);
    gemm_bf16<2, 2><<<dim3(h / 64, h / 64), blk, 0, stream>>>(
        wdl, wh, XsB, nullptr, nullptr, nullptr, nullptr, nullptr,
        h, h, h, dt, 0.f, 0.f, 0.f, 1);
    k_split<<<dim3((int)(hh / 4 / 256)), blk, 0, stream>>>(XsB, XsB_b, nullptr, (int)(hh / 4));
    k_tsplit<<<dim3(h / 32, h / 32), dim3(32, 8), 0, stream>>>(XsB, XsBT_b, nullptr, h, h);
    k_init_EP<<<dim3(h / 256, h), blk, 0, stream>>>(XsB, Eb, nullptr, h);
    {   // Taylor terms k=2..6 (||dtB|| ~ 0.15 -> trunc ~1e-9)
        const unsigned short* a = XsB_b;
        unsigned short* outs[5] = {btA, btB, btA, btB, btA};
        for (int k = 2; k <= 6; ++k) {
            gemm_bf16<2, 2><<<dim3(h / 64, h / 64), blk, 0, stream>>>(
                a, XsBT_b, nullptr, outs[k - 2], nullptr, nullptr, Eb, nullptr,
                h, h, h, 1.f / (float)k, 0.f, 0.f, 0.f, 0);
            a = outs[k - 2];
        }
    }
    k_tsplit<<<dim3(h / 32, h / 32), dim3(32, 8), 0, stream>>>(Eb, EbTh, EbTl, h, h);

    // ============ Phase C: forcing + scan ============
    k_split<<<dim3((int)(nn / 4 / 256)), blk, 0, stream>>>(Ea, Eah, Eal, (int)(nn / 4));
    k_split<<<dim3((int)(nn / 4 / 256)), blk, 0, stream>>>(Pa, Pab, nullptr, (int)(nn / 4));
    k_tsplit<<<dim3(h / 32, n / 32), dim3(32, 8), 0, stream>>>(x0, x0T, nullptr, n, h);
    // forcing = dt * (Pa @ x0)
    gemm_bf16<4, 2><<<dim3(h / 64, n / 128), blk, 0, stream>>>(
        Pab, x0T, forcing, nullptr, nullptr, nullptr, nullptr, nullptr,
        n, h, n, dt, 0.f, 0.f, 0.f, 0);

    // scan: z <- Ea @ z @ Eb + forcing, 9 steps (int(1.0 // 0.1) == 9)
    const float* zin = x;
    for (int s = 1; s <= 9; ++s) {
        k_tsplit<<<dim3(h / 32, n / 32), dim3(32, 8), 0, stream>>>(zin, zTh, zTl, n, h);
        // tb = Ea @ z  (split x split, 3 terms; last one emits tb hi/lo bf16)
        gemm_bf16<4, 2><<<dim3(h / 64, n / 128), blk, 0, stream>>>(
            Eah, zTh, tb, nullptr, nullptr, nullptr, nullptr, nullptr,
            n, h, n, 1.f, 0.f, 0.f, 0.f, 0);
        gemm_bf16<4, 2><<<dim3(h / 64, n / 128), blk, 0, stream>>>(
            Eah, zTl, tb, nullptr, nullptr, nullptr, nullptr, nullptr,
            n, h, n, 1.f, 0.f, 0.f, 0.f, 1);
        gemm_bf16<4, 2><<<dim3(h / 64, n / 128), blk, 0, stream>>>(
            Eal, zTh, tb, tbh, tbl, nullptr, nullptr, nullptr,
            n, h, n, 1.f, 0.f, 0.f, 0.f, 1);
        // zout = tb @ Eb + forcing
        float* zout = (s & 1) ? (float*)d_out : za;
        gemm_bf16<4, 2><<<dim3(h / 64, n / 128), blk, 0, stream>>>(
            tbh, EbTh, zout, nullptr, nullptr, forcing, nullptr, nullptr,
            n, h, h, 1.f, 1.f, 0.f, 0.f, 0);
        gemm_bf16<4, 2><<<dim3(h / 64, n / 128), blk, 0, stream>>>(
            tbh, EbTl, zout, nullptr, nullptr, nullptr, nullptr, nullptr,
            n, h, h, 1.f, 0.f, 0.f, 0.f, 1);
        gemm_bf16<4, 2><<<dim3(h / 64, n / 128), blk, 0, stream>>>(
            tbl, EbTh, zout, nullptr, nullptr, nullptr, nullptr, nullptr,
            n, h, h, 1.f, 0.f, 0.f, 0.f, 1);
        zin = zout;
    }
}

// Round 3
// 1032.186 us; speedup vs baseline: 6.0931x; 2.3026x over previous
//
#include <hip/hip_runtime.h>

typedef __attribute__((ext_vector_type(8))) short short8v;
typedef __attribute__((ext_vector_type(4))) float f32x4;

typedef const __attribute__((address_space(1))) void gvoid_t;
typedef __attribute__((address_space(3))) void svoid_t;

__device__ __forceinline__ unsigned short f2b(float f) {
    unsigned u = __float_as_uint(f);
    unsigned r = (u + 0x7fffu + ((u >> 16) & 1u)) >> 16;
    return (unsigned short)r;
}
__device__ __forceinline__ float b2f(unsigned short h) {
    return __uint_as_float((unsigned)h << 16);
}

// ---------------- elementwise / setup kernels ----------------

// X = dt*A = scale * sigmoid(alpha_i) * (adj - I); also bf16 copy, Ma init = X, Pm init = X/2
__global__ void k_build_A(const float* __restrict__ adj,
                          const float* __restrict__ alpha,
                          float* __restrict__ Xs, unsigned short* __restrict__ Xb,
                          float* __restrict__ Ma, float* __restrict__ Pm,
                          int n, float scale)
{
    int j = blockIdx.x * 256 + threadIdx.x;
    int i = blockIdx.y;
    if (j >= n) return;
    size_t idx = (size_t)i * n + j;
    float s = 1.f / (1.f + expf(-alpha[i]));
    float v = scale * s * (adj[idx] - (i == j ? 1.f : 0.f));
    Xs[idx] = v;
    Xb[idx] = f2b(v);
    Ma[idx] = v;
    Pm[idx] = 0.5f * v;
}

// E = w - I (bf16), Ed = E*diag(clip(d)) (bf16 + f32)
__global__ void k_build_EW(const float* __restrict__ w,
                           const float* __restrict__ d,
                           unsigned short* __restrict__ Eb,
                           unsigned short* __restrict__ Edb,
                           float* __restrict__ Edf, int h)
{
    int j = blockIdx.x * 256 + threadIdx.x;
    int i = blockIdx.y;
    if (j >= h) return;
    size_t idx = (size_t)i * h + j;
    float e = w[idx] - (i == j ? 1.f : 0.f);
    float dc = fminf(fmaxf(d[j], 0.f), 1.f);
    Eb[idx] = f2b(e);
    float ed = e * dc;
    Edb[idx] = f2b(ed);
    Edf[idx] = ed;
}

// R = dt * ( diag(clip(d)-1) + Ed + Ed^T )
__global__ void k_build_R(const float* __restrict__ Ed,
                          const float* __restrict__ d,
                          float* __restrict__ R, int h, float dt)
{
    __shared__ float tile[32][33];
    int bx = blockIdx.x * 32, by = blockIdx.y * 32;
    int tx = threadIdx.x, ty = threadIdx.y;
    #pragma unroll
    for (int r = 0; r < 32; r += 8)
        tile[ty + r][tx] = Ed[(size_t)(bx + ty + r) * h + by + tx];
    __syncthreads();
    #pragma unroll
    for (int r = 0; r < 32; r += 8) {
        int i = by + ty + r, j = bx + tx;
        float v = Ed[(size_t)i * h + j] + tile[tx][ty + r];
        if (i == j) v += fminf(fmaxf(d[i], 0.f), 1.f) - 1.f;
        R[(size_t)i * h + j] = dt * v;
    }
}

// f32 -> bf16 (hi only), vectorized x4
__global__ void k_split(const float* __restrict__ in,
                        unsigned short* __restrict__ hi, int count4)
{
    int i = blockIdx.x * 256 + threadIdx.x;
    if (i >= count4) return;
    float4 v = ((const float4*)in)[i];
    ushort4 h;
    h.x = f2b(v.x); h.y = f2b(v.y); h.z = f2b(v.z); h.w = f2b(v.w);
    ((ushort4*)hi)[i] = h;
}

// transpose: in[R][C] f32 -> out[C][R] bf16
__global__ void k_tsplit(const float* __restrict__ in,
                         unsigned short* __restrict__ outT, int R, int C)
{
    __shared__ float tile[32][33];
    int bx = blockIdx.x * 32, by = blockIdx.y * 32;
    int tx = threadIdx.x, ty = threadIdx.y;
    #pragma unroll
    for (int r = 0; r < 32; r += 8)
        tile[ty + r][tx] = in[(size_t)(by + ty + r) * C + bx + tx];
    __syncthreads();
    #pragma unroll
    for (int r = 0; r < 32; r += 8)
        outT[(size_t)(bx + ty + r) * R + by + tx] = f2b(tile[tx][ty + r]);
}

__global__ void k_copy(const float* __restrict__ in, float* __restrict__ out, int count4)
{
    int i = blockIdx.x * 256 + threadIdx.x;
    if (i >= count4) return;
    ((float4*)out)[i] = ((const float4*)in)[i];
}

// ---------------- bf16 MFMA GEMM ----------------
// v = alpha*(A@B) + beta*D + g2*D2  (per element)
// outputs: C (f32), Cb (bf16 row-major), CbT (bf16 transposed, [N][M])
// accumulators: E += v, P += pfac*v
// A: M x K bf16 row-major.  BT: N x K bf16 row-major (B transposed).
// Tile BM=FM*32 x BN=FN*32, BK=32, 4 waves (2x2). M%BM==0, N%BN==0, K%32==0.

template<int FM, int FN>
__global__ __launch_bounds__(256)
void gemm_bf16(const unsigned short* __restrict__ A,
               const unsigned short* __restrict__ BT,
               float* __restrict__ C,
               unsigned short* __restrict__ Cb,
               unsigned short* __restrict__ CbT,
               const float* __restrict__ D,
               const float* __restrict__ D2,
               float* __restrict__ E, float* __restrict__ P,
               int M, int N, int K,
               float alpha, float beta, float g2, float pfac)
{
    constexpr int BM = FM * 32, BN = FN * 32, BK = 32;
    __shared__ unsigned short As[BM * BK];
    __shared__ unsigned short Bs[BN * BK];

    const int tid  = threadIdx.x;
    const int lane = tid & 63;
    const int wave = tid >> 6;
    const int wr = wave >> 1, wc = wave & 1;
    const int l16 = lane & 15, l4 = lane >> 4;
    const int brow = blockIdx.y * BM, bcol = blockIdx.x * BN;

    f32x4 acc[FM][FN];
    #pragma unroll
    for (int m = 0; m < FM; ++m)
        #pragma unroll
        for (int j = 0; j < FN; ++j)
            acc[m][j] = (f32x4){0.f, 0.f, 0.f, 0.f};

    constexpr int AIT = BM / 64;
    constexpr int BIT = BN / 64;

    const unsigned short* Ab = A + (size_t)brow * K;
    const unsigned short* Bb = BT + (size_t)bcol * K;

    for (int k0 = 0; k0 < K; k0 += BK) {
        #pragma unroll
        for (int it = 0; it < AIT; ++it) {
            int cb = it * 256 + wave * 64;           // wave-uniform chunk base
            int chunk = cb + lane;
            int r = chunk >> 2, c8 = (chunk & 3) * 8;
            __builtin_amdgcn_global_load_lds(
                (gvoid_t*)(Ab + (size_t)r * K + k0 + c8),
                (svoid_t*)(As + cb * 8), 16, 0, 0);
        }
        #pragma unroll
        for (int it = 0; it < BIT; ++it) {
            int cb = it * 256 + wave * 64;
            int chunk = cb + lane;
            int r = chunk >> 2, c8 = (chunk & 3) * 8;
            __builtin_amdgcn_global_load_lds(
                (gvoid_t*)(Bb + (size_t)r * K + k0 + c8),
                (svoid_t*)(Bs + cb * 8), 16, 0, 0);
        }
        __syncthreads();

        short8v af[FM], bfr[FN];
        #pragma unroll
        for (int m = 0; m < FM; ++m)
            af[m] = *(const short8v*)&As[(wr * FM * 16 + m * 16 + l16) * BK + l4 * 8];
        #pragma unroll
        for (int j = 0; j < FN; ++j)
            bfr[j] = *(const short8v*)&Bs[(wc * FN * 16 + j * 16 + l16) * BK + l4 * 8];
        #pragma unroll
        for (int m = 0; m < FM; ++m)
            #pragma unroll
            for (int j = 0; j < FN; ++j)
                acc[m][j] = __builtin_amdgcn_mfma_f32_16x16x32_bf16(
                    af[m], bfr[j], acc[m][j], 0, 0, 0);
        __syncthreads();
    }

    #pragma unroll
    for (int m = 0; m < FM; ++m) {
        #pragma unroll
        for (int j = 0; j < FN; ++j) {
            const int row0 = brow + wr * FM * 16 + m * 16 + l4 * 4;
            const int col  = bcol + wc * FN * 16 + j * 16 + l16;
            float vv[4];
            #pragma unroll
            for (int q = 0; q < 4; ++q) {
                size_t idx = (size_t)(row0 + q) * N + col;
                float v = alpha * acc[m][j][q];
                if (D)  v = fmaf(beta, D[idx], v);
                if (D2) v = fmaf(g2, D2[idx], v);
                vv[q] = v;
                if (C)  C[idx] = v;
                if (Cb) Cb[idx] = f2b(v);
                if (E)  E[idx] += v;
                if (P)  P[idx] += pfac * v;
            }
            if (CbT) {
                ushort4 t4;
                t4.x = f2b(vv[0]); t4.y = f2b(vv[1]);
                t4.z = f2b(vv[2]); t4.w = f2b(vv[3]);
                *reinterpret_cast<ushort4*>(&CbT[(size_t)col * M + row0]) = t4;
            }
        }
    }
}

// ---------------- host orchestration ----------------

extern "C" void kernel_launch(void* const* d_in, const int* in_sizes, int n_in,
                              void* d_out, int out_size, void* d_ws, size_t ws_size,
                              hipStream_t stream)
{
    const float* x     = (const float*)d_in[0];   // [n, h]
    const float* x0    = (const float*)d_in[1];   // [n, h]
    const float* adj   = (const float*)d_in[2];   // [n, n]
    const float* alpha = (const float*)d_in[3];   // [n]
    const float* w     = (const float*)d_in[4];   // [h, h]
    const float* dvec  = (const float*)d_in[5];   // [h]

    const int n = in_sizes[3];      // 2048
    const int h = in_sizes[5];      // 1024
    const size_t MB = 1u << 20;
    char* ws = (char*)d_ws;

    const size_t nn = (size_t)n * n;
    const size_t hh = (size_t)h * h;

    // ---- workspace (MiB offsets, phase-overlaid; peak 72 MiB) ----
    // Phase A
    float*          Xs   = (float*)(ws + 0 * MB);            // 16
    unsigned short* XAb  = (unsigned short*)(ws + 16 * MB);  // 8 (dies after T2 gemm)
    unsigned short* XAT  = (unsigned short*)(ws + 24 * MB);  // 8 (dies after T3 gemm)
    float*          Ma   = (float*)(ws + 32 * MB);           // 16 (dies after split)
    float*          Pm   = (float*)(ws + 48 * MB);           // 16 (dies after split)
    unsigned short* T2b  = (unsigned short*)(ws + 64 * MB);  // 8 (dies after T3 gemm)
    unsigned short* Mah  = (unsigned short*)(ws + 16 * MB);  // 8 (persists; over XAb)
    unsigned short* Pmb  = (unsigned short*)(ws + 64 * MB);  // 8 (over T2b; dies after forcing)
    // Phase B (in [32,62); phase-A f32 temps dead)
    unsigned short* Eb_  = (unsigned short*)(ws + 32 * MB);  // 2
    unsigned short* Edb  = (unsigned short*)(ws + 34 * MB);  // 2
    float*          Edf  = (float*)(ws + 36 * MB);           // 4
    float*          R    = (float*)(ws + 40 * MB);           // 4
    float*          XB   = (float*)(ws + 44 * MB);           // 4
    unsigned short* XBb  = (unsigned short*)(ws + 48 * MB);  // 2
    unsigned short* XBT  = (unsigned short*)(ws + 50 * MB);  // 2
    unsigned short* bt0  = (unsigned short*)(ws + 52 * MB);  // 2
    unsigned short* bt1  = (unsigned short*)(ws + 54 * MB);  // 2
    float*          Mb   = (float*)(ws + 56 * MB);           // 4
    unsigned short* MbT  = (unsigned short*)(ws + 60 * MB);  // 2 (persists)
    // Phase C
    unsigned short* x0T  = (unsigned short*)(ws + 0 * MB);   // 4 (over Xs, dead)
    float*          F    = (float*)(ws + 4 * MB);            // 8 (persists)
    unsigned short* zt   = (unsigned short*)(ws + 12 * MB);  // 4 (persists)
    float*          tf   = (float*)(ws + 32 * MB);           // 8 (over Eb_/Edb/Edf)
    unsigned short* tb16 = (unsigned short*)(ws + 40 * MB);  // 4 (over R)
    float*          za   = (float*)(ws + 44 * MB);           // 8 (over XB/XBb/XBT)

    const dim3 blk(256);
    const float dt = 0.1f;

    // ============ Phase A: Ma = e^{dtA}-I, Pm = phi1(dtA)-I (order 3) ============
    k_build_A<<<dim3(n / 256, n), blk, 0, stream>>>(adj, alpha, Xs, XAb, Ma, Pm, n, 0.5f * dt);
    k_tsplit<<<dim3(n / 32, n / 32), dim3(32, 8), 0, stream>>>(Xs, XAT, n, n);
    // k=2: v = X^2/2 ; Ma += v ; Pm += v/3 ; T2b = bf16(v)
    gemm_bf16<4, 4><<<dim3(n / 128, n / 128), blk, 0, stream>>>(
        XAb, XAT, nullptr, T2b, nullptr, nullptr, nullptr, Ma, Pm,
        n, n, n, 0.5f, 0.f, 0.f, 1.f / 3.f);
    // k=3: v = T2*X/3 = X^3/6 ; Ma += v ; Pm += v/4
    gemm_bf16<4, 4><<<dim3(n / 128, n / 128), blk, 0, stream>>>(
        T2b, XAT, nullptr, nullptr, nullptr, nullptr, nullptr, Ma, Pm,
        n, n, n, 1.f / 3.f, 0.f, 0.f, 0.25f);
    k_split<<<dim3((int)(nn / 4 / 256)), blk, 0, stream>>>(Ma, Mah, (int)(nn / 4));
    k_split<<<dim3((int)(nn / 4 / 256)), blk, 0, stream>>>(Pm, Pmb, (int)(nn / 4));

    // ============ Phase B: Mb = e^{dtB}-I (order 7) ============
    // B = diag(dc-1) + Ed + Ed^T + Ed E^T, with E = w - I, Ed = E diag(dc)
    k_build_EW<<<dim3(h / 256, h), blk, 0, stream>>>(w, dvec, Eb_, Edb, Edf, h);
    k_build_R<<<dim3(h / 32, h / 32), dim3(32, 8), 0, stream>>>(Edf, dvec, R, h, dt);
    // XB = dt*(Ed @ E^T) + R   (BT of E^T is E itself)
    gemm_bf16<2, 2><<<dim3(h / 64, h / 64), blk, 0, stream>>>(
        Edb, Eb_, XB, nullptr, nullptr, R, nullptr, nullptr, nullptr,
        h, h, h, dt, 1.f, 0.f, 0.f);
    k_split<<<dim3((int)(hh / 4 / 256)), blk, 0, stream>>>(XB, XBb, (int)(hh / 4));
    k_tsplit<<<dim3(h / 32, h / 32), dim3(32, 8), 0, stream>>>(XB, XBT, h, h);
    k_copy<<<dim3((int)(hh / 4 / 256)), blk, 0, stream>>>(XB, Mb, (int)(hh / 4));
    {   // Taylor k=2..7: term_k = term_{k-1} * XB / k ; Mb += term
        const unsigned short* a = XBb;
        unsigned short* outs[6] = {bt0, bt1, bt0, bt1, bt0, nullptr};
        for (int k = 2; k <= 7; ++k) {
            gemm_bf16<2, 2><<<dim3(h / 64, h / 64), blk, 0, stream>>>(
                a, XBT, nullptr, outs[k - 2], nullptr, nullptr, nullptr, Mb, nullptr,
                h, h, h, 1.f / (float)k, 0.f, 0.f, 0.f);
            a = outs[k - 2];
        }
    }
    k_tsplit<<<dim3(h / 32, h / 32), dim3(32, 8), 0, stream>>>(Mb, MbT, h, h);

    // ============ Phase C: forcing + scan ============
    k_tsplit<<<dim3(h / 32, n / 32), dim3(32, 8), 0, stream>>>(x0, x0T, n, h);
    // F = dt*(x0 + Pm @ x0)
    gemm_bf16<4, 2><<<dim3(h / 64, n / 128), blk, 0, stream>>>(
        Pmb, x0T, F, nullptr, nullptr, x0, nullptr, nullptr, nullptr,
        n, h, n, dt, dt, 0.f, 0.f);
    // zt = x^T bf16
    k_tsplit<<<dim3(h / 32, n / 32), dim3(32, 8), 0, stream>>>(x, zt, n, h);

    // scan: t = z + Ma z ; z' = t + t Mb + F   (9 steps: int(1.0 // 0.1) == 9)
    const float* zf = x;
    for (int s = 1; s <= 9; ++s) {
        gemm_bf16<4, 2><<<dim3(h / 64, n / 128), blk, 0, stream>>>(
            Mah, zt, tf, tb16, nullptr, zf, nullptr, nullptr, nullptr,
            n, h, n, 1.f, 1.f, 0.f, 0.f);
        float* zout = (s == 9) ? (float*)d_out : za;
        gemm_bf16<4, 2><<<dim3(h / 64, n / 128), blk, 0, stream>>>(
            tb16, MbT, zout, nullptr, (s == 9) ? nullptr : zt, tf, F, nullptr, nullptr,
            n, h, h, 1.f, 1.f, 1.f, 0.f);
        zf = za;
    }
}

// Round 4
// 820.995 us; speedup vs baseline: 7.6604x; 1.2572x over previous
//
#include <hip/hip_runtime.h>

typedef __attribute__((ext_vector_type(8))) short short8v;
typedef __attribute__((ext_vector_type(4))) float f32x4;

typedef const __attribute__((address_space(1))) void gvoid_t;
typedef __attribute__((address_space(3))) void svoid_t;

__device__ __forceinline__ unsigned short f2b(float f) {
    unsigned u = __float_as_uint(f);
    unsigned r = (u + 0x7fffu + ((u >> 16) & 1u)) >> 16;
    return (unsigned short)r;
}
__device__ __forceinline__ float b2f(unsigned short h) {
    return __uint_as_float((unsigned)h << 16);
}

// ---------------- elementwise / setup kernels ----------------

// X = dt*A = scale * sigmoid(alpha_i) * (adj - I)  -> f32 + bf16
__global__ void k_build_A(const float* __restrict__ adj,
                          const float* __restrict__ alpha,
                          float* __restrict__ Xs, unsigned short* __restrict__ Xb,
                          int n, float scale)
{
    int j = blockIdx.x * 256 + threadIdx.x;
    int i = blockIdx.y;
    if (j >= n) return;
    size_t idx = (size_t)i * n + j;
    float s = 1.f / (1.f + expf(-alpha[i]));
    float v = scale * s * (adj[idx] - (i == j ? 1.f : 0.f));
    Xs[idx] = v;
    Xb[idx] = f2b(v);
}

// E = w - I (bf16), Ed = E*diag(clip(d)) (bf16 + f32)
__global__ void k_build_EW(const float* __restrict__ w,
                           const float* __restrict__ d,
                           unsigned short* __restrict__ Eb,
                           unsigned short* __restrict__ Edb,
                           float* __restrict__ Edf, int h)
{
    int j = blockIdx.x * 256 + threadIdx.x;
    int i = blockIdx.y;
    if (j >= h) return;
    size_t idx = (size_t)i * h + j;
    float e = w[idx] - (i == j ? 1.f : 0.f);
    float dc = fminf(fmaxf(d[j], 0.f), 1.f);
    Eb[idx] = f2b(e);
    float ed = e * dc;
    Edb[idx] = f2b(ed);
    Edf[idx] = ed;
}

// R = dt * ( diag(clip(d)-1) + Ed + Ed^T )
__global__ void k_build_R(const float* __restrict__ Ed,
                          const float* __restrict__ d,
                          float* __restrict__ R, int h, float dt)
{
    __shared__ float tile[32][33];
    int bx = blockIdx.x * 32, by = blockIdx.y * 32;
    int tx = threadIdx.x, ty = threadIdx.y;
    #pragma unroll
    for (int r = 0; r < 32; r += 8)
        tile[ty + r][tx] = Ed[(size_t)(bx + ty + r) * h + by + tx];
    __syncthreads();
    #pragma unroll
    for (int r = 0; r < 32; r += 8) {
        int i = by + ty + r, j = bx + tx;
        float v = Ed[(size_t)i * h + j] + tile[tx][ty + r];
        if (i == j) v += fminf(fmaxf(d[i], 0.f), 1.f) - 1.f;
        R[(size_t)i * h + j] = dt * v;
    }
}

// transpose: in[R][C] f32 -> out[C][R] bf16
__global__ void k_tsplit(const float* __restrict__ in,
                         unsigned short* __restrict__ outT, int R, int C)
{
    __shared__ float tile[32][33];
    int bx = blockIdx.x * 32, by = blockIdx.y * 32;
    int tx = threadIdx.x, ty = threadIdx.y;
    #pragma unroll
    for (int r = 0; r < 32; r += 8)
        tile[ty + r][tx] = in[(size_t)(by + ty + r) * C + bx + tx];
    __syncthreads();
    #pragma unroll
    for (int r = 0; r < 32; r += 8)
        outT[(size_t)(bx + ty + r) * R + by + tx] = f2b(tile[tx][ty + r]);
}

// ---------------- bf16 MFMA GEMM, 2-phase double-buffered ----------------
// acc = A @ B  (A: MxK bf16 row-major; BT: NxK bf16 row-major = B transposed)
// v  = alpha*acc + beta*D + g2*D2 + g3*b2f(Db)     -> C (f32), Cb (bf16), CbT (bf16 [N][M])
// v2 = pa*acc + pb*D + pc*b2f(Db)                  -> Cb2 (bf16)
// Tile BM=FM*32 x BN=FN*32, BK=64, 4 waves (2x2). M%BM==0, N%BN==0, K%64==0.
// LDS: linear dest for global_load_lds; XOR-swizzled global source + swizzled
// ds_read (chunk ^= row&7) -> conflict-free b128 reads (rule #21 both-sides).

template<int FM, int FN>
__global__ __launch_bounds__(256)
void gemm_bf16(const unsigned short* __restrict__ A,
               const unsigned short* __restrict__ BT,
               float* __restrict__ C,
               unsigned short* __restrict__ Cb,
               unsigned short* __restrict__ Cb2,
               unsigned short* __restrict__ CbT,
               const float* __restrict__ D,
               const float* __restrict__ D2,
               const unsigned short* __restrict__ Db,
               int M, int N, int K,
               float alpha, float beta, float g2, float g3,
               float pa, float pb, float pc)
{
    constexpr int BM = FM * 32, BN = FN * 32, BK = 64;
    __shared__ unsigned short As[2][BM * BK];
    __shared__ unsigned short Bs[2][BN * BK];

    const int tid  = threadIdx.x;
    const int lane = tid & 63;
    const int wave = tid >> 6;
    const int wr = wave >> 1, wc = wave & 1;
    const int l16 = lane & 15, l4 = lane >> 4;
    const int brow = blockIdx.y * BM, bcol = blockIdx.x * BN;

    f32x4 acc[FM][FN];
    #pragma unroll
    for (int m = 0; m < FM; ++m)
        #pragma unroll
        for (int j = 0; j < FN; ++j)
            acc[m][j] = (f32x4){0.f, 0.f, 0.f, 0.f};

    constexpr int AIT = BM / 32;   // 16B chunks per thread for A tile (BM*8/256)
    constexpr int BIT = BN / 32;

    const unsigned short* Ab = A + (size_t)brow * K;
    const unsigned short* Bb = BT + (size_t)bcol * K;
    const int nt = K / BK;

    auto stage = [&](int b, int k0) {
        #pragma unroll
        for (int it = 0; it < AIT; ++it) {
            int cb = it * 256 + wave * 64;          // wave-uniform chunk base
            int ch = cb + lane;
            int r = ch >> 3, c = ch & 7;
            int cs = c ^ (r & 7);                   // inverse-swizzled source
            __builtin_amdgcn_global_load_lds(
                (gvoid_t*)(Ab + (size_t)r * K + k0 + cs * 8),
                (svoid_t*)(&As[b][cb * 8]), 16, 0, 0);
        }
        #pragma unroll
        for (int it = 0; it < BIT; ++it) {
            int cb = it * 256 + wave * 64;
            int ch = cb + lane;
            int r = ch >> 3, c = ch & 7;
            int cs = c ^ (r & 7);
            __builtin_amdgcn_global_load_lds(
                (gvoid_t*)(Bb + (size_t)r * K + k0 + cs * 8),
                (svoid_t*)(&Bs[b][cb * 8]), 16, 0, 0);
        }
    };

    stage(0, 0);
    __syncthreads();

    int cur = 0;
    for (int t = 0; t < nt; ++t) {
        if (t + 1 < nt) stage(cur ^ 1, (t + 1) * BK);   // prefetch next tile

        short8v af[FM][2], bf[FN][2];
        #pragma unroll
        for (int m = 0; m < FM; ++m) {
            int r = wr * FM * 16 + m * 16 + l16;
            #pragma unroll
            for (int hf = 0; hf < 2; ++hf) {
                int cs = (hf * 4 + l4) ^ (r & 7);        // swizzled read
                af[m][hf] = *(const short8v*)&As[cur][r * BK + cs * 8];
            }
        }
        #pragma unroll
        for (int j = 0; j < FN; ++j) {
            int r = wc * FN * 16 + j * 16 + l16;
            #pragma unroll
            for (int hf = 0; hf < 2; ++hf) {
                int cs = (hf * 4 + l4) ^ (r & 7);
                bf[j][hf] = *(const short8v*)&Bs[cur][r * BK + cs * 8];
            }
        }
        #pragma unroll
        for (int hf = 0; hf < 2; ++hf)
            #pragma unroll
            for (int m = 0; m < FM; ++m)
                #pragma unroll
                for (int j = 0; j < FN; ++j)
                    acc[m][j] = __builtin_amdgcn_mfma_f32_16x16x32_bf16(
                        af[m][hf], bf[j][hf], acc[m][j], 0, 0, 0);

        __syncthreads();   // vmcnt(0): next tile staged; lgkm already drained
        cur ^= 1;
    }

    #pragma unroll
    for (int m = 0; m < FM; ++m) {
        #pragma unroll
        for (int j = 0; j < FN; ++j) {
            const int row0 = brow + wr * FM * 16 + m * 16 + l4 * 4;
            const int col  = bcol + wc * FN * 16 + j * 16 + l16;
            float vv[4];
            #pragma unroll
            for (int q = 0; q < 4; ++q) {
                size_t idx = (size_t)(row0 + q) * N + col;
                float a0 = acc[m][j][q];
                float v = alpha * a0;
                float dv = 0.f, dbv = 0.f;
                if (D)  { dv = D[idx]; v = fmaf(beta, dv, v); }
                if (D2) v = fmaf(g2, D2[idx], v);
                if (Db) { dbv = b2f(Db[idx]); v = fmaf(g3, dbv, v); }
                vv[q] = v;
                if (C)  C[idx] = v;
                if (Cb) Cb[idx] = f2b(v);
                if (Cb2) {
                    float v2 = pa * a0;
                    if (D)  v2 = fmaf(pb, dv, v2);
                    if (Db) v2 = fmaf(pc, dbv, v2);
                    Cb2[idx] = f2b(v2);
                }
            }
            if (CbT) {
                ushort4 t4;
                t4.x = f2b(vv[0]); t4.y = f2b(vv[1]);
                t4.z = f2b(vv[2]); t4.w = f2b(vv[3]);
                *reinterpret_cast<ushort4*>(&CbT[(size_t)col * M + row0]) = t4;
            }
        }
    }
}

// ---------------- host orchestration ----------------

extern "C" void kernel_launch(void* const* d_in, const int* in_sizes, int n_in,
                              void* d_out, int out_size, void* d_ws, size_t ws_size,
                              hipStream_t stream)
{
    const float* x     = (const float*)d_in[0];   // [n, h]
    const float* x0    = (const float*)d_in[1];   // [n, h]
    const float* adj   = (const float*)d_in[2];   // [n, n]
    const float* alpha = (const float*)d_in[3];   // [n]
    const float* w     = (const float*)d_in[4];   // [h, h]
    const float* dvec  = (const float*)d_in[5];   // [h]

    const int n = in_sizes[3];      // 2048
    const int h = in_sizes[5];      // 1024
    const size_t MB = 1u << 20;
    char* ws = (char*)d_ws;

    // ---- workspace (MiB offsets, phase-overlaid; peak 70 MiB) ----
    float*          Xs   = (float*)(ws + 0 * MB);            // 16, dies after A2
    float*          tf   = (float*)(ws + 0 * MB);            // 8  (scan)
    float*          za   = (float*)(ws + 8 * MB);            // 8  (scan)
    unsigned short* XAb  = (unsigned short*)(ws + 16 * MB);  // 8, dies after A1
    unsigned short* Eb_  = (unsigned short*)(ws + 16 * MB);  // 2  (phase B)
    unsigned short* Edb  = (unsigned short*)(ws + 18 * MB);  // 2
    float*          Edf  = (float*)(ws + 20 * MB);           // 4
    unsigned short* XAT  = (unsigned short*)(ws + 24 * MB);  // 8, dies after A2
    float*          R    = (float*)(ws + 24 * MB);           // 4  (phase B)
    float*          XBf  = (float*)(ws + 28 * MB);           // 4
    unsigned short* T2b  = (unsigned short*)(ws + 32 * MB);  // 8, dies after A2
    unsigned short* XBb  = (unsigned short*)(ws + 32 * MB);  // 2  (phase B)
    unsigned short* XBT  = (unsigned short*)(ws + 34 * MB);  // 2
    unsigned short* t2b  = (unsigned short*)(ws + 36 * MB);  // 2
    unsigned short* t3b  = (unsigned short*)(ws + 38 * MB);  // 2
    unsigned short* Mah  = (unsigned short*)(ws + 40 * MB);  // 8 persists
    unsigned short* Pmb  = (unsigned short*)(ws + 48 * MB);  // 8, dies after F
    unsigned short* tb16 = (unsigned short*)(ws + 48 * MB);  // 4  (scan)
    unsigned short* zt   = (unsigned short*)(ws + 52 * MB);  // 4  (scan)
    float*          S3   = (float*)(ws + 56 * MB);           // 4  (phase B)
    unsigned short* x0T  = (unsigned short*)(ws + 56 * MB);  // 4  (phase C pre)
    unsigned short* MbT  = (unsigned short*)(ws + 60 * MB);  // 2 persists
    float*          F    = (float*)(ws + 62 * MB);           // 8 persists

    const dim3 blk(256);
    const float dt = 0.1f;

    // ============ Phase A: Mah = bf16(e^{dtA}-I), Pmb = bf16(phi1(dtA)-I) ============
    k_build_A<<<dim3(n / 256, n), blk, 0, stream>>>(adj, alpha, Xs, XAb, n, 0.5f * dt);
    k_tsplit<<<dim3(n / 32, n / 32), dim3(32, 8), 0, stream>>>(Xs, XAT, n, n);
    // A1: T2b = bf16(X^2/2)
    gemm_bf16<4, 2><<<dim3(n / 64, n / 128), blk, 0, stream>>>(
        XAb, XAT, nullptr, T2b, nullptr, nullptr, nullptr, nullptr, nullptr,
        n, n, n, 0.5f, 0.f, 0.f, 0.f, 0.f, 0.f, 0.f);
    // A2: acc = T2@X ; Ma = acc/3 + Xs + T2 -> Mah ; Pm = acc/12 + Xs/2 + T2/3 -> Pmb
    gemm_bf16<4, 2><<<dim3(n / 64, n / 128), blk, 0, stream>>>(
        T2b, XAT, nullptr, Mah, Pmb, nullptr, Xs, nullptr, T2b,
        n, n, n, 1.f / 3.f, 1.f, 0.f, 1.f, 1.f / 12.f, 0.5f, 1.f / 3.f);

    // ============ Phase B: MbT = bf16((e^{dtB}-I)^T), order 4 ============
    k_build_EW<<<dim3(h / 256, h), blk, 0, stream>>>(w, dvec, Eb_, Edb, Edf, h);
    k_build_R<<<dim3(h / 32, h / 32), dim3(32, 8), 0, stream>>>(Edf, dvec, R, h, dt);
    // XB = dt*(Ed @ E^T) + R  -> f32 + bf16 + bf16^T
    gemm_bf16<2, 2><<<dim3(h / 64, h / 64), blk, 0, stream>>>(
        Edb, Eb_, XBf, XBb, nullptr, XBT, R, nullptr, nullptr,
        h, h, h, dt, 1.f, 0.f, 0.f, 0.f, 0.f, 0.f);
    // k2: t2b = bf16(XB^2/2)
    gemm_bf16<2, 2><<<dim3(h / 64, h / 64), blk, 0, stream>>>(
        XBb, XBT, nullptr, t2b, nullptr, nullptr, nullptr, nullptr, nullptr,
        h, h, h, 0.5f, 0.f, 0.f, 0.f, 0.f, 0.f, 0.f);
    // k3: acc = t2@XB ; S3 = acc/3 + XBf + t2 (f32) ; t3b = bf16(acc/3)
    gemm_bf16<2, 2><<<dim3(h / 64, h / 64), blk, 0, stream>>>(
        t2b, XBT, S3, nullptr, t3b, nullptr, XBf, nullptr, t2b,
        h, h, h, 1.f / 3.f, 1.f, 0.f, 1.f, 1.f / 3.f, 0.f, 0.f);
    // k4: Mb = acc/4 + S3 -> MbT (transposed bf16)
    gemm_bf16<2, 2><<<dim3(h / 64, h / 64), blk, 0, stream>>>(
        t3b, XBT, nullptr, nullptr, nullptr, MbT, S3, nullptr, nullptr,
        h, h, h, 0.25f, 1.f, 0.f, 0.f, 0.f, 0.f, 0.f);

    // ============ Phase C: forcing + scan ============
    k_tsplit<<<dim3(h / 32, n / 32), dim3(32, 8), 0, stream>>>(x0, x0T, n, h);
    // F = dt*(Pm @ x0) + dt*x0
    gemm_bf16<4, 2><<<dim3(h / 64, n / 128), blk, 0, stream>>>(
        Pmb, x0T, F, nullptr, nullptr, nullptr, x0, nullptr, nullptr,
        n, h, n, dt, dt, 0.f, 0.f, 0.f, 0.f, 0.f);
    k_tsplit<<<dim3(h / 32, n / 32), dim3(32, 8), 0, stream>>>(x, zt, n, h);

    // scan: t = z + Ma z ; z' = t + t Mb + F   (9 steps: int(1.0 // 0.1) == 9)
    const float* zf = x;
    for (int s = 1; s <= 9; ++s) {
        // G1: tf = Ma@z + z ; tb16 = bf16(tf)
        gemm_bf16<4, 2><<<dim3(h / 64, n / 128), blk, 0, stream>>>(
            Mah, zt, tf, tb16, nullptr, nullptr, zf, nullptr, nullptr,
            n, h, n, 1.f, 1.f, 0.f, 0.f, 0.f, 0.f, 0.f);
        // G2: z' = tb@Mb + tf + F ; emit z' (f32) and z'^T (bf16) for next step
        float* zout = (s == 9) ? (float*)d_out : za;
        gemm_bf16<4, 2><<<dim3(h / 64, n / 128), blk, 0, stream>>>(
            tb16, MbT, zout, nullptr, nullptr, (s == 9) ? nullptr : zt,
            tf, F, nullptr,
            n, h, h, 1.f, 1.f, 1.f, 0.f, 0.f, 0.f, 0.f);
        zf = za;
    }
}

// Round 5
// 618.867 us; speedup vs baseline: 10.1624x; 1.3266x over previous
//
#include <hip/hip_runtime.h>

typedef __attribute__((ext_vector_type(8))) short short8v;
typedef __attribute__((ext_vector_type(4))) float f32x4;

typedef const __attribute__((address_space(1))) void gvoid_t;
typedef __attribute__((address_space(3))) void svoid_t;

__device__ __forceinline__ unsigned short f2b(float f) {
    unsigned u = __float_as_uint(f);
    unsigned r = (u + 0x7fffu + ((u >> 16) & 1u)) >> 16;
    return (unsigned short)r;
}
__device__ __forceinline__ float b2f(unsigned short h) {
    return __uint_as_float((unsigned)h << 16);
}

// ---------------- elementwise / setup kernels ----------------

// X = dt*A = scale * sigmoid(alpha_i) * (adj - I)  -> f32 + bf16
__global__ void k_build_A(const float* __restrict__ adj,
                          const float* __restrict__ alpha,
                          float* __restrict__ Xs, unsigned short* __restrict__ Xb,
                          int n, float scale)
{
    int j = blockIdx.x * 256 + threadIdx.x;
    int i = blockIdx.y;
    if (j >= n) return;
    size_t idx = (size_t)i * n + j;
    float s = 1.f / (1.f + expf(-alpha[i]));
    float v = scale * s * (adj[idx] - (i == j ? 1.f : 0.f));
    Xs[idx] = v;
    Xb[idx] = f2b(v);
}

// E = w - I (bf16), Ed = E*diag(clip(d)) (bf16 + f32)
__global__ void k_build_EW(const float* __restrict__ w,
                           const float* __restrict__ d,
                           unsigned short* __restrict__ Eb,
                           unsigned short* __restrict__ Edb,
                           float* __restrict__ Edf, int h)
{
    int j = blockIdx.x * 256 + threadIdx.x;
    int i = blockIdx.y;
    if (j >= h) return;
    size_t idx = (size_t)i * h + j;
    float e = w[idx] - (i == j ? 1.f : 0.f);
    float dc = fminf(fmaxf(d[j], 0.f), 1.f);
    Eb[idx] = f2b(e);
    float ed = e * dc;
    Edb[idx] = f2b(ed);
    Edf[idx] = ed;
}

// R = dt * ( diag(clip(d)-1) + Ed + Ed^T )
__global__ void k_build_R(const float* __restrict__ Ed,
                          const float* __restrict__ d,
                          float* __restrict__ R, int h, float dt)
{
    __shared__ float tile[32][33];
    int bx = blockIdx.x * 32, by = blockIdx.y * 32;
    int tx = threadIdx.x, ty = threadIdx.y;
    #pragma unroll
    for (int r = 0; r < 32; r += 8)
        tile[ty + r][tx] = Ed[(size_t)(bx + ty + r) * h + by + tx];
    __syncthreads();
    #pragma unroll
    for (int r = 0; r < 32; r += 8) {
        int i = by + ty + r, j = bx + tx;
        float v = Ed[(size_t)i * h + j] + tile[tx][ty + r];
        if (i == j) v += fminf(fmaxf(d[i], 0.f), 1.f) - 1.f;
        R[(size_t)i * h + j] = dt * v;
    }
}

// transpose: in[R][C] f32 -> out[C][R] bf16
__global__ void k_tsplit(const float* __restrict__ in,
                         unsigned short* __restrict__ outT, int R, int C)
{
    __shared__ float tile[32][33];
    int bx = blockIdx.x * 32, by = blockIdx.y * 32;
    int tx = threadIdx.x, ty = threadIdx.y;
    #pragma unroll
    for (int r = 0; r < 32; r += 8)
        tile[ty + r][tx] = in[(size_t)(by + ty + r) * C + bx + tx];
    __syncthreads();
    #pragma unroll
    for (int r = 0; r < 32; r += 8)
        outT[(size_t)(bx + ty + r) * R + by + tx] = f2b(tile[tx][ty + r]);
}

// ------- bf16 MFMA GEMM, counted-vmcnt double-buffered pipeline -------
// acc = A @ B  (A: MxK bf16 row-major; BT: NxK bf16 row-major = B transposed)
// v  = alpha*acc + beta*D + g2*D2 + g3*b2f(Db)  -> C (f32), Cb (bf16), CbT ([N][M] bf16)
// v2 = pa*acc + pb*D + pc*b2f(Db)               -> Cb2 (bf16)
// 512 threads = 8 waves in 4x2; per-wave FM*16 x FN*16 frags of 16x16.
// BM = 64*FM, BN = 32*FN, BK = 64.  M%BM==0, N%BN==0, K%128==0 (nt>=2).
// LDS: linear global_load_lds dest; XOR-swizzled source + swizzled ds_read.
// K-loop: raw s_barrier + s_waitcnt vmcnt(LPT) (counted, never 0 mid-loop).

template<int FM, int FN>
__global__ __launch_bounds__(512, 4)
void gemm_bf16(const unsigned short* __restrict__ A,
               const unsigned short* __restrict__ BT,
               float* __restrict__ C,
               unsigned short* __restrict__ Cb,
               unsigned short* __restrict__ Cb2,
               unsigned short* __restrict__ CbT,
               const float* __restrict__ D,
               const float* __restrict__ D2,
               const unsigned short* __restrict__ Db,
               int M, int N, int K,
               float alpha, float beta, float g2, float g3,
               float pa, float pb, float pc)
{
    constexpr int BM = FM * 64, BN = FN * 32, BK = 64;
    constexpr int AIT = FM;          // 16B chunks per thread, A tile (BM*8/512)
    constexpr int BIT = FN / 2;      // (BN*8/512)
    constexpr int LPT = AIT + BIT;   // loads in flight per staged tile
    __shared__ unsigned short As[2][BM * BK];
    __shared__ unsigned short Bs[2][BN * BK];

    const int tid  = threadIdx.x;
    const int lane = tid & 63;
    const int wave = tid >> 6;
    const int wr = wave >> 1, wc = wave & 1;   // 4 x 2 wave grid
    const int l16 = lane & 15, l4 = lane >> 4;
    const int brow = blockIdx.y * BM, bcol = blockIdx.x * BN;

    f32x4 acc[FM][FN];
    #pragma unroll
    for (int m = 0; m < FM; ++m)
        #pragma unroll
        for (int j = 0; j < FN; ++j)
            acc[m][j] = (f32x4){0.f, 0.f, 0.f, 0.f};

    const unsigned short* Ab = A + (size_t)brow * K;
    const unsigned short* Bb = BT + (size_t)bcol * K;
    const int nt = K / BK;

    auto stage = [&](int b, int k0) {
        #pragma unroll
        for (int it = 0; it < AIT; ++it) {
            int cb = it * 512 + wave * 64;          // wave-uniform chunk base
            int ch = cb + lane;
            int r = ch >> 3, c = ch & 7;
            int cs = c ^ (r & 7);                   // inverse-swizzled source
            __builtin_amdgcn_global_load_lds(
                (gvoid_t*)(Ab + (size_t)r * K + k0 + cs * 8),
                (svoid_t*)(&As[b][cb * 8]), 16, 0, 0);
        }
        #pragma unroll
        for (int it = 0; it < BIT; ++it) {
            int cb = it * 512 + wave * 64;
            int ch = cb + lane;
            int r = ch >> 3, c = ch & 7;
            int cs = c ^ (r & 7);
            __builtin_amdgcn_global_load_lds(
                (gvoid_t*)(Bb + (size_t)r * K + k0 + cs * 8),
                (svoid_t*)(&Bs[b][cb * 8]), 16, 0, 0);
        }
    };

    stage(0, 0);
    stage(1, BK);

    for (int t = 0; t < nt; ++t) {
        const int cur = t & 1;
        if (t + 1 < nt) {
            asm volatile("s_waitcnt vmcnt(%0)" :: "i"(LPT) : "memory");
        } else {
            asm volatile("s_waitcnt vmcnt(0)" ::: "memory");
        }
        __builtin_amdgcn_s_barrier();
        asm volatile("" ::: "memory");
        __builtin_amdgcn_sched_barrier(0);

        short8v af[FM][2], bf[FN][2];
        #pragma unroll
        for (int m = 0; m < FM; ++m) {
            int r = wr * FM * 16 + m * 16 + l16;
            #pragma unroll
            for (int hf = 0; hf < 2; ++hf) {
                int cs = (hf * 4 + l4) ^ (r & 7);    // swizzled read
                af[m][hf] = *(const short8v*)&As[cur][r * BK + cs * 8];
            }
        }
        #pragma unroll
        for (int j = 0; j < FN; ++j) {
            int r = wc * FN * 16 + j * 16 + l16;
            #pragma unroll
            for (int hf = 0; hf < 2; ++hf) {
                int cs = (hf * 4 + l4) ^ (r & 7);
                bf[j][hf] = *(const short8v*)&Bs[cur][r * BK + cs * 8];
            }
        }
        __builtin_amdgcn_s_setprio(1);
        #pragma unroll
        for (int hf = 0; hf < 2; ++hf)
            #pragma unroll
            for (int m = 0; m < FM; ++m)
                #pragma unroll
                for (int j = 0; j < FN; ++j)
                    acc[m][j] = __builtin_amdgcn_mfma_f32_16x16x32_bf16(
                        af[m][hf], bf[j][hf], acc[m][j], 0, 0, 0);
        __builtin_amdgcn_s_setprio(0);
        __builtin_amdgcn_sched_barrier(0);
        __builtin_amdgcn_s_barrier();
        asm volatile("" ::: "memory");
        if (t + 2 < nt) stage(cur, (t + 2) * BK);   // reuse just-freed buffer
    }

    #pragma unroll
    for (int m = 0; m < FM; ++m) {
        #pragma unroll
        for (int j = 0; j < FN; ++j) {
            const int row0 = brow + wr * FM * 16 + m * 16 + l4 * 4;
            const int col  = bcol + wc * FN * 16 + j * 16 + l16;
            float vv[4];
            #pragma unroll
            for (int q = 0; q < 4; ++q) {
                size_t idx = (size_t)(row0 + q) * N + col;
                float a0 = acc[m][j][q];
                float v = alpha * a0;
                float dv = 0.f, dbv = 0.f;
                if (D)  { dv = D[idx]; v = fmaf(beta, dv, v); }
                if (D2) v = fmaf(g2, D2[idx], v);
                if (Db) { dbv = b2f(Db[idx]); v = fmaf(g3, dbv, v); }
                vv[q] = v;
                if (C)  C[idx] = v;
                if (Cb) Cb[idx] = f2b(v);
                if (Cb2) {
                    float v2 = pa * a0;
                    if (D)  v2 = fmaf(pb, dv, v2);
                    if (Db) v2 = fmaf(pc, dbv, v2);
                    Cb2[idx] = f2b(v2);
                }
            }
            if (CbT) {
                ushort4 t4;
                t4.x = f2b(vv[0]); t4.y = f2b(vv[1]);
                t4.z = f2b(vv[2]); t4.w = f2b(vv[3]);
                *reinterpret_cast<ushort4*>(&CbT[(size_t)col * M + row0]) = t4;
            }
        }
    }
}

// ---------------- host orchestration ----------------

extern "C" void kernel_launch(void* const* d_in, const int* in_sizes, int n_in,
                              void* d_out, int out_size, void* d_ws, size_t ws_size,
                              hipStream_t stream)
{
    const float* x     = (const float*)d_in[0];   // [n, h]
    const float* x0    = (const float*)d_in[1];   // [n, h]
    const float* adj   = (const float*)d_in[2];   // [n, n]
    const float* alpha = (const float*)d_in[3];   // [n]
    const float* w     = (const float*)d_in[4];   // [h, h]
    const float* dvec  = (const float*)d_in[5];   // [h]

    const int n = in_sizes[3];      // 2048
    const int h = in_sizes[5];      // 1024
    const size_t MB = 1u << 20;
    char* ws = (char*)d_ws;

    // ---- workspace (MiB offsets, phase-overlaid; peak 70 MiB) ----
    float*          Xs   = (float*)(ws + 0 * MB);            // 16, dies after A2
    float*          tf   = (float*)(ws + 0 * MB);            // 8  (scan)
    float*          za   = (float*)(ws + 8 * MB);            // 8  (scan)
    unsigned short* XAb  = (unsigned short*)(ws + 16 * MB);  // 8, dies after A1
    unsigned short* Eb_  = (unsigned short*)(ws + 16 * MB);  // 2  (phase B)
    unsigned short* Edb  = (unsigned short*)(ws + 18 * MB);  // 2
    float*          Edf  = (float*)(ws + 20 * MB);           // 4
    unsigned short* XAT  = (unsigned short*)(ws + 24 * MB);  // 8, dies after A2
    float*          R    = (float*)(ws + 24 * MB);           // 4  (phase B)
    float*          XBf  = (float*)(ws + 28 * MB);           // 4
    unsigned short* T2b  = (unsigned short*)(ws + 32 * MB);  // 8, dies after A2
    unsigned short* XBb  = (unsigned short*)(ws + 32 * MB);  // 2  (phase B)
    unsigned short* XBT  = (unsigned short*)(ws + 34 * MB);  // 2
    unsigned short* t2b  = (unsigned short*)(ws + 36 * MB);  // 2
    unsigned short* t3b  = (unsigned short*)(ws + 38 * MB);  // 2
    unsigned short* Mah  = (unsigned short*)(ws + 40 * MB);  // 8 persists
    unsigned short* Pmb  = (unsigned short*)(ws + 48 * MB);  // 8, dies after F
    unsigned short* tb16 = (unsigned short*)(ws + 48 * MB);  // 4  (scan)
    unsigned short* zt   = (unsigned short*)(ws + 52 * MB);  // 4  (scan)
    float*          S3   = (float*)(ws + 56 * MB);           // 4  (phase B)
    unsigned short* x0T  = (unsigned short*)(ws + 56 * MB);  // 4  (phase C pre)
    unsigned short* MbT  = (unsigned short*)(ws + 60 * MB);  // 2 persists
    float*          F    = (float*)(ws + 62 * MB);           // 8 persists

    const dim3 blk(256);
    const dim3 blk512(512);
    const float dt = 0.1f;

    // ============ Phase A: Mah = bf16(e^{dtA}-I), Pmb = bf16(phi1(dtA)-I) ============
    k_build_A<<<dim3(n / 256, n), blk, 0, stream>>>(adj, alpha, Xs, XAb, n, 0.5f * dt);
    k_tsplit<<<dim3(n / 32, n / 32), dim3(32, 8), 0, stream>>>(Xs, XAT, n, n);
    // A1: T2b = bf16(X^2/2)
    gemm_bf16<2, 2><<<dim3(n / 64, n / 128), blk512, 0, stream>>>(
        XAb, XAT, nullptr, T2b, nullptr, nullptr, nullptr, nullptr, nullptr,
        n, n, n, 0.5f, 0.f, 0.f, 0.f, 0.f, 0.f, 0.f);
    // A2: acc = T2@X ; Ma = acc/3 + Xs + T2 -> Mah ; Pm = acc/12 + Xs/2 + T2/3 -> Pmb
    gemm_bf16<2, 2><<<dim3(n / 64, n / 128), blk512, 0, stream>>>(
        T2b, XAT, nullptr, Mah, Pmb, nullptr, Xs, nullptr, T2b,
        n, n, n, 1.f / 3.f, 1.f, 0.f, 1.f, 1.f / 12.f, 0.5f, 1.f / 3.f);

    // ============ Phase B: MbT = bf16((e^{dtB}-I)^T), order 4 ============
    k_build_EW<<<dim3(h / 256, h), blk, 0, stream>>>(w, dvec, Eb_, Edb, Edf, h);
    k_build_R<<<dim3(h / 32, h / 32), dim3(32, 8), 0, stream>>>(Edf, dvec, R, h, dt);
    // XB = dt*(Ed @ E^T) + R  -> f32 + bf16 + bf16^T
    gemm_bf16<1, 2><<<dim3(h / 64, h / 64), blk512, 0, stream>>>(
        Edb, Eb_, XBf, XBb, nullptr, XBT, R, nullptr, nullptr,
        h, h, h, dt, 1.f, 0.f, 0.f, 0.f, 0.f, 0.f);
    // k2: t2b = bf16(XB^2/2)
    gemm_bf16<1, 2><<<dim3(h / 64, h / 64), blk512, 0, stream>>>(
        XBb, XBT, nullptr, t2b, nullptr, nullptr, nullptr, nullptr, nullptr,
        h, h, h, 0.5f, 0.f, 0.f, 0.f, 0.f, 0.f, 0.f);
    // k3: acc = t2@XB ; S3 = acc/3 + XBf + t2 (f32) ; t3b = bf16(acc/3)
    gemm_bf16<1, 2><<<dim3(h / 64, h / 64), blk512, 0, stream>>>(
        t2b, XBT, S3, nullptr, t3b, nullptr, XBf, nullptr, t2b,
        h, h, h, 1.f / 3.f, 1.f, 0.f, 1.f, 1.f / 3.f, 0.f, 0.f);
    // k4: Mb = acc/4 + S3 -> MbT (transposed bf16)
    gemm_bf16<1, 2><<<dim3(h / 64, h / 64), blk512, 0, stream>>>(
        t3b, XBT, nullptr, nullptr, nullptr, MbT, S3, nullptr, nullptr,
        h, h, h, 0.25f, 1.f, 0.f, 0.f, 0.f, 0.f, 0.f);

    // ============ Phase C: forcing + scan ============
    k_tsplit<<<dim3(h / 32, n / 32), dim3(32, 8), 0, stream>>>(x0, x0T, n, h);
    // F = dt*(Pm @ x0) + dt*x0
    gemm_bf16<2, 2><<<dim3(h / 64, n / 128), blk512, 0, stream>>>(
        Pmb, x0T, F, nullptr, nullptr, nullptr, x0, nullptr, nullptr,
        n, h, n, dt, dt, 0.f, 0.f, 0.f, 0.f, 0.f);
    k_tsplit<<<dim3(h / 32, n / 32), dim3(32, 8), 0, stream>>>(x, zt, n, h);

    // scan: t = z + Ma z ; z' = t + t Mb + F   (9 steps: int(1.0 // 0.1) == 9)
    const float* zf = x;
    for (int s = 1; s <= 9; ++s) {
        // G1: tf = Ma@z + z ; tb16 = bf16(tf)
        gemm_bf16<2, 2><<<dim3(h / 64, n / 128), blk512, 0, stream>>>(
            Mah, zt, tf, tb16, nullptr, nullptr, zf, nullptr, nullptr,
            n, h, n, 1.f, 1.f, 0.f, 0.f, 0.f, 0.f, 0.f);
        // G2: z' = tb@Mb + tf + F ; emit z' (f32) and z'^T (bf16) for next step
        float* zout = (s == 9) ? (float*)d_out : za;
        gemm_bf16<2, 2><<<dim3(h / 64, n / 128), blk512, 0, stream>>>(
            tb16, MbT, zout, nullptr, nullptr, (s == 9) ? nullptr : zt,
            tf, F, nullptr,
            n, h, h, 1.f, 1.f, 1.f, 0.f, 0.f, 0.f, 0.f);
        zf = za;
    }
}

// Round 6
// 427.046 us; speedup vs baseline: 14.7272x; 1.4492x over previous
//
#include <hip/hip_runtime.h>

typedef __attribute__((ext_vector_type(8))) short short8v;
typedef __attribute__((ext_vector_type(4))) float f32x4;

typedef const __attribute__((address_space(1))) void gvoid_t;
typedef __attribute__((address_space(3))) void svoid_t;

__device__ __forceinline__ unsigned short f2b(float f) {
    unsigned u = __float_as_uint(f);
    unsigned r = (u + 0x7fffu + ((u >> 16) & 1u)) >> 16;
    return (unsigned short)r;
}
__device__ __forceinline__ float b2f(unsigned short h) {
    return __uint_as_float((unsigned)h << 16);
}

// ---------------- elementwise / setup kernels ----------------

// X = dt*A = scale * sigmoid(alpha_i) * (adj - I)  -> f32 + bf16
__global__ void k_build_A(const float* __restrict__ adj,
                          const float* __restrict__ alpha,
                          float* __restrict__ Xs, unsigned short* __restrict__ Xb,
                          int n, float scale)
{
    int j = blockIdx.x * 256 + threadIdx.x;
    int i = blockIdx.y;
    if (j >= n) return;
    size_t idx = (size_t)i * n + j;
    float s = 1.f / (1.f + expf(-alpha[i]));
    float v = scale * s * (adj[idx] - (i == j ? 1.f : 0.f));
    Xs[idx] = v;
    Xb[idx] = f2b(v);
}

// E = w - I (bf16), Ed = E*diag(clip(d)) (bf16 + f32)
__global__ void k_build_EW(const float* __restrict__ w,
                           const float* __restrict__ d,
                           unsigned short* __restrict__ Eb,
                           unsigned short* __restrict__ Edb,
                           float* __restrict__ Edf, int h)
{
    int j = blockIdx.x * 256 + threadIdx.x;
    int i = blockIdx.y;
    if (j >= h) return;
    size_t idx = (size_t)i * h + j;
    float e = w[idx] - (i == j ? 1.f : 0.f);
    float dc = fminf(fmaxf(d[j], 0.f), 1.f);
    Eb[idx] = f2b(e);
    float ed = e * dc;
    Edb[idx] = f2b(ed);
    Edf[idx] = ed;
}

// R = dt * ( diag(clip(d)-1) + Ed + Ed^T )
__global__ void k_build_R(const float* __restrict__ Ed,
                          const float* __restrict__ d,
                          float* __restrict__ R, int h, float dt)
{
    __shared__ float tile[32][33];
    int bx = blockIdx.x * 32, by = blockIdx.y * 32;
    int tx = threadIdx.x, ty = threadIdx.y;
    #pragma unroll
    for (int r = 0; r < 32; r += 8)
        tile[ty + r][tx] = Ed[(size_t)(bx + ty + r) * h + by + tx];
    __syncthreads();
    #pragma unroll
    for (int r = 0; r < 32; r += 8) {
        int i = by + ty + r, j = bx + tx;
        float v = Ed[(size_t)i * h + j] + tile[tx][ty + r];
        if (i == j) v += fminf(fmaxf(d[i], 0.f), 1.f) - 1.f;
        R[(size_t)i * h + j] = dt * v;
    }
}

// transpose: in[R][C] f32 -> out[C][R] bf16
__global__ void k_tsplit(const float* __restrict__ in,
                         unsigned short* __restrict__ outT, int R, int C)
{
    __shared__ float tile[32][33];
    int bx = blockIdx.x * 32, by = blockIdx.y * 32;
    int tx = threadIdx.x, ty = threadIdx.y;
    #pragma unroll
    for (int r = 0; r < 32; r += 8)
        tile[ty + r][tx] = in[(size_t)(by + ty + r) * C + bx + tx];
    __syncthreads();
    #pragma unroll
    for (int r = 0; r < 32; r += 8)
        outT[(size_t)(bx + ty + r) * R + by + tx] = f2b(tile[tx][ty + r]);
}

// ------- bf16 MFMA GEMM: 4-buffer depth-2 single-barrier pipeline -------
// acc = A @ B  (A: MxK bf16 row-major; BT: NxK bf16 row-major = B transposed)
// v  = alpha*acc + beta*D + g2*D2 + g3*b2f(Db) -> C (f32), Cb (bf16), CbT ([N][M] bf16)
// v2 = pa*acc + pb*D + pc*b2f(Db)              -> Cb2 (bf16)
// v3 = qa*acc + qb*D + qc*b2f(Db)              -> Cb3 (bf16)
// 512 threads = 8 waves (4x2). BM = 64*FM, BN = 32*FN, BK = 64.
// K-loop per step: {stage(t+2); s_waitcnt vmcnt(2*LPT); s_barrier; ds_read; MFMA}
// -> ONE barrier/step, staged tile has ~2.5 steps of latency budget; buffer
// recycle distance 4 (!=3 mod 4) makes overwrite-before-read impossible.
// LDS: linear global_load_lds dest; XOR-swizzled source + swizzled ds_read.
// SWZ: grid must be (16,16); each XCD gets an 8x4 block rect (L2 locality).

template<int FM, int FN, bool SWZ>
__global__ __launch_bounds__(512, 2)
void gemm_bf16(const unsigned short* __restrict__ A,
               const unsigned short* __restrict__ BT,
               float* __restrict__ C,
               unsigned short* __restrict__ Cb,
               unsigned short* __restrict__ Cb2,
               unsigned short* __restrict__ Cb3,
               unsigned short* __restrict__ CbT,
               const float* __restrict__ D,
               const float* __restrict__ D2,
               const unsigned short* __restrict__ Db,
               int M, int N, int K,
               float alpha, float beta, float g2, float g3,
               float pa, float pb, float pc,
               float qa, float qb, float qc)
{
    constexpr int BM = FM * 64, BN = FN * 32, BK = 64;
    constexpr int AIT = FM;          // 16B chunks/thread for A tile
    constexpr int BIT = FN / 2;
    constexpr int LPT = AIT + BIT;   // loads in flight per staged tile
    __shared__ unsigned short As[4][BM * BK];
    __shared__ unsigned short Bs[4][BN * BK];

    int bx = blockIdx.x, by = blockIdx.y;
    if (SWZ) {   // bijective for 16x16 grids: XCD q owns an 8x4 rect
        int bid = by * 16 + bx;
        int q = bid & 7, c = bid >> 3;
        by = (q & 1) * 8 + (c & 7);
        bx = (q >> 1) * 4 + (c >> 3);
    }

    const int tid  = threadIdx.x;
    const int lane = tid & 63;
    const int wave = tid >> 6;
    const int wr = wave >> 1, wc = wave & 1;   // 4 x 2 wave grid
    const int l16 = lane & 15, l4 = lane >> 4;
    const int brow = by * BM, bcol = bx * BN;

    f32x4 acc[FM][FN];
    #pragma unroll
    for (int m = 0; m < FM; ++m)
        #pragma unroll
        for (int j = 0; j < FN; ++j)
            acc[m][j] = (f32x4){0.f, 0.f, 0.f, 0.f};

    const unsigned short* Ab = A + (size_t)brow * K;
    const unsigned short* Bb = BT + (size_t)bcol * K;
    const int nt = K / BK;

    auto stage = [&](int b, int k0) {
        #pragma unroll
        for (int it = 0; it < AIT; ++it) {
            int cb = it * 512 + wave * 64;          // wave-uniform chunk base
            int ch = cb + lane;
            int r = ch >> 3, cc = ch & 7;
            int cs = cc ^ (r & 7);                  // inverse-swizzled source
            __builtin_amdgcn_global_load_lds(
                (gvoid_t*)(Ab + (size_t)r * K + k0 + cs * 8),
                (svoid_t*)(&As[b][cb * 8]), 16, 0, 0);
        }
        #pragma unroll
        for (int it = 0; it < BIT; ++it) {
            int cb = it * 512 + wave * 64;
            int ch = cb + lane;
            int r = ch >> 3, cc = ch & 7;
            int cs = cc ^ (r & 7);
            __builtin_amdgcn_global_load_lds(
                (gvoid_t*)(Bb + (size_t)r * K + k0 + cs * 8),
                (svoid_t*)(&Bs[b][cb * 8]), 16, 0, 0);
        }
    };

    stage(0, 0);
    stage(1, BK);

    for (int t = 0; t < nt; ++t) {
        const int cur = t & 3;
        if (t + 2 < nt) stage((t + 2) & 3, (t + 2) * BK);

        const int rem = nt - 1 - t;
        if (rem >= 2)      asm volatile("s_waitcnt vmcnt(%0)" :: "i"(2 * LPT) : "memory");
        else if (rem == 1) asm volatile("s_waitcnt vmcnt(%0)" :: "i"(LPT) : "memory");
        else               asm volatile("s_waitcnt vmcnt(0)" ::: "memory");
        __builtin_amdgcn_s_barrier();
        asm volatile("" ::: "memory");
        __builtin_amdgcn_sched_barrier(0);

        short8v af[FM][2], bf[FN][2];
        #pragma unroll
        for (int m = 0; m < FM; ++m) {
            int r = wr * FM * 16 + m * 16 + l16;
            #pragma unroll
            for (int hf = 0; hf < 2; ++hf) {
                int cs = (hf * 4 + l4) ^ (r & 7);    // swizzled read
                af[m][hf] = *(const short8v*)&As[cur][r * BK + cs * 8];
            }
        }
        #pragma unroll
        for (int j = 0; j < FN; ++j) {
            int r = wc * FN * 16 + j * 16 + l16;
            #pragma unroll
            for (int hf = 0; hf < 2; ++hf) {
                int cs = (hf * 4 + l4) ^ (r & 7);
                bf[j][hf] = *(const short8v*)&Bs[cur][r * BK + cs * 8];
            }
        }
        __builtin_amdgcn_s_setprio(1);
        #pragma unroll
        for (int hf = 0; hf < 2; ++hf)
            #pragma unroll
            for (int m = 0; m < FM; ++m)
                #pragma unroll
                for (int j = 0; j < FN; ++j)
                    acc[m][j] = __builtin_amdgcn_mfma_f32_16x16x32_bf16(
                        af[m][hf], bf[j][hf], acc[m][j], 0, 0, 0);
        __builtin_amdgcn_s_setprio(0);
        __builtin_amdgcn_sched_barrier(0);
    }

    #pragma unroll
    for (int m = 0; m < FM; ++m) {
        #pragma unroll
        for (int j = 0; j < FN; ++j) {
            const int row0 = brow + wr * FM * 16 + m * 16 + l4 * 4;
            const int col  = bcol + wc * FN * 16 + j * 16 + l16;
            float vv[4];
            #pragma unroll
            for (int q = 0; q < 4; ++q) {
                size_t idx = (size_t)(row0 + q) * N + col;
                float a0 = acc[m][j][q];
                float v = alpha * a0;
                float dv = 0.f, dbv = 0.f;
                if (D)  { dv = D[idx]; v = fmaf(beta, dv, v); }
                if (D2) v = fmaf(g2, D2[idx], v);
                if (Db) { dbv = b2f(Db[idx]); v = fmaf(g3, dbv, v); }
                vv[q] = v;
                if (C)  C[idx] = v;
                if (Cb) Cb[idx] = f2b(v);
                if (Cb2) {
                    float v2 = pa * a0;
                    if (D)  v2 = fmaf(pb, dv, v2);
                    if (Db) v2 = fmaf(pc, dbv, v2);
                    Cb2[idx] = f2b(v2);
                }
                if (Cb3) {
                    float v3 = qa * a0;
                    if (D)  v3 = fmaf(qb, dv, v3);
                    if (Db) v3 = fmaf(qc, dbv, v3);
                    Cb3[idx] = f2b(v3);
                }
            }
            if (CbT) {
                ushort4 t4;
                t4.x = f2b(vv[0]); t4.y = f2b(vv[1]);
                t4.z = f2b(vv[2]); t4.w = f2b(vv[3]);
                *reinterpret_cast<ushort4*>(&CbT[(size_t)col * M + row0]) = t4;
            }
        }
    }
}

// ---------------- host orchestration ----------------

extern "C" void kernel_launch(void* const* d_in, const int* in_sizes, int n_in,
                              void* d_out, int out_size, void* d_ws, size_t ws_size,
                              hipStream_t stream)
{
    const float* x     = (const float*)d_in[0];   // [n, h]
    const float* x0    = (const float*)d_in[1];   // [n, h]
    const float* adj   = (const float*)d_in[2];   // [n, n]
    const float* alpha = (const float*)d_in[3];   // [n]
    const float* w     = (const float*)d_in[4];   // [h, h]
    const float* dvec  = (const float*)d_in[5];   // [h]

    const int n = in_sizes[3];      // 2048
    const int h = in_sizes[5];      // 1024
    const size_t MB = 1u << 20;
    char* ws = (char*)d_ws;

    typedef unsigned short u16;
    // ---- workspace (MiB offsets, phase-overlaid; peak 106 MiB) ----
    float* Xs    = (float*)(ws + 0 * MB);    // 16  phase A (dies after A2)
    float* tf    = (float*)(ws + 0 * MB);    // 8   scan
    float* za    = (float*)(ws + 8 * MB);    // 8   scan
    u16*   XAb   = (u16*)(ws + 16 * MB);     // 8   dies after A1
    u16*   Eb_   = (u16*)(ws + 16 * MB);     // 2   phase B
    u16*   Edb   = (u16*)(ws + 18 * MB);     // 2
    float* Edf   = (float*)(ws + 20 * MB);   // 4
    u16*   XAT   = (u16*)(ws + 24 * MB);     // 8   dies after A2
    float* R     = (float*)(ws + 24 * MB);   // 4   phase B
    float* XBf   = (float*)(ws + 28 * MB);   // 4
    u16*   T2b   = (u16*)(ws + 32 * MB);     // 8   dies after A2
    u16*   XBb   = (u16*)(ws + 32 * MB);     // 2   phase B
    u16*   XBT   = (u16*)(ws + 34 * MB);     // 2
    u16*   t2b   = (u16*)(ws + 36 * MB);     // 2
    u16*   t3b   = (u16*)(ws + 38 * MB);     // 2
    u16*   Mah   = (u16*)(ws + 40 * MB);     // 8   persists (single step)
    u16*   Pmb   = (u16*)(ws + 48 * MB);     // 8   dies after F
    u16*   tb16  = (u16*)(ws + 48 * MB);     // 4   scan
    u16*   zt    = (u16*)(ws + 52 * MB);     // 4   scan
    u16*   M2ah  = (u16*)(ws + 56 * MB);     // 8   persists (dbl steps)
    float* S3    = (float*)(ws + 64 * MB);   // 4   phase B
    u16*   x0T   = (u16*)(ws + 64 * MB);     // 4   phase C pre (S3 dead)
    u16*   MbT   = (u16*)(ws + 68 * MB);     // 2   persists
    u16*   Mbb   = (u16*)(ws + 70 * MB);     // 2   dies after B5
    u16*   FTb   = (u16*)(ws + 72 * MB);     // 4   dies after u-gemm
    u16*   M2bTb = (u16*)(ws + 76 * MB);     // 2   persists (dbl steps)
    float* Ff    = (float*)(ws + 78 * MB);   // 8   persists
    float* uf    = (float*)(ws + 86 * MB);   // 8   dies after F2
    u16*   ub    = (u16*)(ws + 94 * MB);     // 4   dies after F2
    float* F2f   = (float*)(ws + 98 * MB);   // 8   persists (dbl steps)

    const dim3 blk(256);
    const dim3 blk512(512);
    const dim3 g16(16, 16);
    const float dt = 0.1f;
    const u16* nu16 = nullptr;
    const float* nf32 = nullptr;

    // ===== Phase A: Mah=bf16(e^X-I), Pmb=bf16(phi1-I), M2ah=bf16(e^{2X}-I) =====
    k_build_A<<<dim3(n / 256, n), blk, 0, stream>>>(adj, alpha, Xs, XAb, n, 0.5f * dt);
    k_tsplit<<<dim3(n / 32, n / 32), dim3(32, 8), 0, stream>>>(Xs, XAT, n, n);
    // A1: T2b = bf16(X^2)
    gemm_bf16<2, 4, true><<<g16, blk512, 0, stream>>>(
        XAb, XAT, nullptr, T2b, nullptr, nullptr, nullptr, nf32, nf32, nu16,
        n, n, n, 1.f, 0.f, 0.f, 0.f, 0.f, 0.f, 0.f, 0.f, 0.f, 0.f);
    // A2: acc = X^2@X = X^3
    //   Ma  = X + X^2/2 + X^3/6        -> Mah  (alpha=1/6, D=Xs b=1, Db=T2b g3=1/2)
    //   Pm  = X/2 + X^2/6 + X^3/24     -> Pmb  (pa=1/24, pb=1/2, pc=1/6)
    //   M2a = 2X + 2X^2 + (4/3)X^3     -> M2ah (qa=4/3, qb=2, qc=2)
    gemm_bf16<2, 4, true><<<g16, blk512, 0, stream>>>(
        T2b, XAT, nullptr, Mah, Pmb, M2ah, nullptr, Xs, nf32, T2b,
        n, n, n, 1.f / 6.f, 1.f, 0.f, 0.5f,
        1.f / 24.f, 0.5f, 1.f / 6.f, 4.f / 3.f, 2.f, 2.f);

    // ===== Phase B: Mb = e^{dtB}-I (order 4), M2bT = (Mb^2+2Mb)^T =====
    k_build_EW<<<dim3(h / 256, h), blk, 0, stream>>>(w, dvec, Eb_, Edb, Edf, h);
    k_build_R<<<dim3(h / 32, h / 32), dim3(32, 8), 0, stream>>>(Edf, dvec, R, h, dt);
    // B1: XB = dt*(Ed @ E^T) + R
    gemm_bf16<1, 2, true><<<g16, blk512, 0, stream>>>(
        Edb, Eb_, XBf, XBb, nullptr, nullptr, XBT, R, nf32, nu16,
        h, h, h, dt, 1.f, 0.f, 0.f, 0.f, 0.f, 0.f, 0.f, 0.f, 0.f);
    // B2: t2b = bf16(XB^2/2)
    gemm_bf16<1, 2, true><<<g16, blk512, 0, stream>>>(
        XBb, XBT, nullptr, t2b, nullptr, nullptr, nullptr, nf32, nf32, nu16,
        h, h, h, 0.5f, 0.f, 0.f, 0.f, 0.f, 0.f, 0.f, 0.f, 0.f, 0.f);
    // B3: acc = t2@XB = XB^3/2 ; S3 = acc/3 + XBf + t2 ; t3b = bf16(acc/3)
    gemm_bf16<1, 2, true><<<g16, blk512, 0, stream>>>(
        t2b, XBT, S3, nullptr, t3b, nullptr, nullptr, XBf, nf32, t2b,
        h, h, h, 1.f / 3.f, 1.f, 0.f, 1.f, 1.f / 3.f, 0.f, 0.f, 0.f, 0.f, 0.f);
    // B4: Mb = acc/4 + S3 -> MbT (CbT) + Mbb (Cb)
    gemm_bf16<1, 2, true><<<g16, blk512, 0, stream>>>(
        t3b, XBT, nullptr, Mbb, nullptr, nullptr, MbT, S3, nf32, nu16,
        h, h, h, 0.25f, 1.f, 0.f, 0.f, 0.f, 0.f, 0.f, 0.f, 0.f, 0.f);
    // B5: M2b^T = (Mb^T)^2 + 2 Mb^T  (A=MbT, B=Mb^T so BT=Mbb)
    gemm_bf16<1, 2, true><<<g16, blk512, 0, stream>>>(
        MbT, Mbb, nullptr, M2bTb, nullptr, nullptr, nullptr, nf32, nf32, MbT,
        h, h, h, 1.f, 0.f, 0.f, 2.f, 0.f, 0.f, 0.f, 0.f, 0.f, 0.f);

    // ===== Phase C: forcing chain =====
    k_tsplit<<<dim3(h / 32, n / 32), dim3(32, 8), 0, stream>>>(x0, x0T, n, h);
    // F = dt*(Pm@x0) + dt*x0 -> Ff + FTb
    gemm_bf16<2, 2, true><<<g16, blk512, 0, stream>>>(
        Pmb, x0T, Ff, nullptr, nullptr, nullptr, FTb, x0, nf32, nu16,
        n, h, n, dt, dt, 0.f, 0.f, 0.f, 0.f, 0.f, 0.f, 0.f, 0.f);
    // u = Ma@F + F -> uf + ub
    gemm_bf16<2, 2, true><<<g16, blk512, 0, stream>>>(
        Mah, FTb, uf, ub, nullptr, nullptr, nullptr, Ff, nf32, nu16,
        n, h, n, 1.f, 1.f, 0.f, 0.f, 0.f, 0.f, 0.f, 0.f, 0.f, 0.f);
    // F2 = u@Mb + u + F
    gemm_bf16<2, 2, true><<<g16, blk512, 0, stream>>>(
        ub, MbT, F2f, nullptr, nullptr, nullptr, nullptr, uf, Ff, nu16,
        n, h, h, 1.f, 1.f, 1.f, 0.f, 0.f, 0.f, 0.f, 0.f, 0.f, 0.f);

    // ===== scan: 4 double-steps + 1 single step (total 9 = int(1.0//0.1)) =====
    k_tsplit<<<dim3(h / 32, n / 32), dim3(32, 8), 0, stream>>>(x, zt, n, h);
    const float* zf = x;
    for (int s = 0; s < 4; ++s) {
        // G1: tf = M2a@z + z ; tb16 = bf16(tf)
        gemm_bf16<2, 2, true><<<g16, blk512, 0, stream>>>(
            M2ah, zt, tf, tb16, nullptr, nullptr, nullptr, zf, nf32, nu16,
            n, h, n, 1.f, 1.f, 0.f, 0.f, 0.f, 0.f, 0.f, 0.f, 0.f, 0.f);
        // G2: z'' = t@M2b + t + F2 -> za (f32) + zt (bf16 transposed)
        gemm_bf16<2, 2, true><<<g16, blk512, 0, stream>>>(
            tb16, M2bTb, za, nullptr, nullptr, nullptr, zt, tf, F2f, nu16,
            n, h, h, 1.f, 1.f, 1.f, 0.f, 0.f, 0.f, 0.f, 0.f, 0.f, 0.f);
        zf = za;
    }
    // single step: tf = Ma@z + z ; out = t@Mb + t + F
    gemm_bf16<2, 2, true><<<g16, blk512, 0, stream>>>(
        Mah, zt, tf, tb16, nullptr, nullptr, nullptr, za, nf32, nu16,
        n, h, n, 1.f, 1.f, 0.f, 0.f, 0.f, 0.f, 0.f, 0.f, 0.f, 0.f);
    gemm_bf16<2, 2, true><<<g16, blk512, 0, stream>>>(
        tb16, MbT, (float*)d_out, nullptr, nullptr, nullptr, nullptr, tf, Ff, nu16,
        n, h, h, 1.f, 1.f, 1.f, 0.f, 0.f, 0.f, 0.f, 0.f, 0.f, 0.f);
}